// Round 1
// baseline (2078.079 us; speedup 1.0000x reference)
//
#include <hip/hip_runtime.h>
#include <math.h>

#define SRC_LEN  1024
#define BSZ      64
#define CDIM     1024
#define ADIM     1024
#define KDIM     1024
#define NEG_MASK -1000000.0f

// ---------------------------------------------------------------------------
// Tiled fp32 GEMM computing acc = A @ W^T over 64x64 tiles, BK=16, 4x4 micro.
// A: [M][1024] row-major.  W: [N][1024] row-major (rows n0..n0+63 used).
// MODE 0: out[m*ADIM + n] = acc + bias[n]                       (dec proj)
// MODE 1: scores[m] += sum_n tanh(acc + bias[n] + dec[(m&63)*ADIM+n]) * v[n]
//         (atomicAdd, block-level reduced first)                (main fused)
// ---------------------------------------------------------------------------
template<int MODE>
__global__ __launch_bounds__(256)
void gemm_kernel(const float* __restrict__ A,
                 const float* __restrict__ W,
                 const float* __restrict__ bias,
                 const float* __restrict__ dec,
                 const float* __restrict__ v,
                 float* __restrict__ out)
{
    const int m0  = blockIdx.x * 64;
    const int n0  = blockIdx.y * 64;
    const int tid = threadIdx.x;
    const int tx  = tid & 15;   // col group 0..15
    const int ty  = tid >> 4;   // row group 0..15

    __shared__ float As[16][64];   // [k][m]
    __shared__ float Bs[16][64];   // [k][n]
    __shared__ float red[64][17];  // epilogue reduction (MODE 1)

    float acc[4][4];
#pragma unroll
    for (int i = 0; i < 4; ++i)
#pragma unroll
        for (int j = 0; j < 4; ++j) acc[i][j] = 0.f;

    const int lr = tid >> 2;        // 0..63 : row within tile
    const int lk = (tid & 3) * 4;   // 0,4,8,12 : k offset

    for (int kb = 0; kb < KDIM; kb += 16) {
        float4 a4 = *reinterpret_cast<const float4*>(&A[(size_t)(m0 + lr) * KDIM + kb + lk]);
        float4 b4 = *reinterpret_cast<const float4*>(&W[(size_t)(n0 + lr) * KDIM + kb + lk]);
        __syncthreads();   // previous iteration's LDS reads complete
        As[lk + 0][lr] = a4.x; As[lk + 1][lr] = a4.y;
        As[lk + 2][lr] = a4.z; As[lk + 3][lr] = a4.w;
        Bs[lk + 0][lr] = b4.x; Bs[lk + 1][lr] = b4.y;
        Bs[lk + 2][lr] = b4.z; Bs[lk + 3][lr] = b4.w;
        __syncthreads();
#pragma unroll
        for (int k = 0; k < 16; ++k) {
            float4 av = *reinterpret_cast<const float4*>(&As[k][ty * 4]);
            float4 bv = *reinterpret_cast<const float4*>(&Bs[k][tx * 4]);
            float am[4] = {av.x, av.y, av.z, av.w};
            float bn[4] = {bv.x, bv.y, bv.z, bv.w};
#pragma unroll
            for (int i = 0; i < 4; ++i)
#pragma unroll
                for (int j = 0; j < 4; ++j)
                    acc[i][j] = fmaf(am[i], bn[j], acc[i][j]);
        }
    }

    if (MODE == 0) {
#pragma unroll
        for (int i = 0; i < 4; ++i) {
            int m = m0 + ty * 4 + i;
#pragma unroll
            for (int j = 0; j < 4; ++j) {
                int n = n0 + tx * 4 + j;
                out[(size_t)m * ADIM + n] = acc[i][j] + bias[n];
            }
        }
    } else {
        float part[4];
#pragma unroll
        for (int i = 0; i < 4; ++i) {
            int m  = m0 + ty * 4 + i;
            int bb = m & (BSZ - 1);
            float p = 0.f;
#pragma unroll
            for (int j = 0; j < 4; ++j) {
                int n = n0 + tx * 4 + j;
                float h = tanhf(acc[i][j] + bias[n] + dec[(size_t)bb * ADIM + n]);
                p = fmaf(h, v[n], p);
            }
            part[i] = p;
        }
        __syncthreads();
#pragma unroll
        for (int i = 0; i < 4; ++i) red[ty * 4 + i][tx] = part[i];
        __syncthreads();
        if (tid < 64) {
            float s = 0.f;
#pragma unroll
            for (int t = 0; t < 16; ++t) s += red[tid][t];
            atomicAdd(&out[m0 + tid], s);
        }
    }
}

// ---------------------------------------------------------------------------
// Masked softmax over S per batch column, in place on the attn buffer.
// One block per b. scores layout: [s*BSZ + b].
// ---------------------------------------------------------------------------
__global__ __launch_bounds__(256)
void softmax_kernel(const int* __restrict__ lens, float* __restrict__ attn)
{
    const int b   = blockIdx.x;
    const int tid = threadIdx.x;
    const int len = lens[b];

    float sc[4];
#pragma unroll
    for (int k = 0; k < 4; ++k) {
        int s = k * 256 + tid;
        float x = attn[(size_t)s * BSZ + b];
        sc[k] = (s < len) ? x : NEG_MASK;
    }

    __shared__ float red[8];

    // --- max reduce ---
    float m = fmaxf(fmaxf(sc[0], sc[1]), fmaxf(sc[2], sc[3]));
#pragma unroll
    for (int off = 32; off > 0; off >>= 1) m = fmaxf(m, __shfl_xor(m, off));
    if ((tid & 63) == 0) red[tid >> 6] = m;
    __syncthreads();
    m = fmaxf(fmaxf(red[0], red[1]), fmaxf(red[2], red[3]));

    // --- exp + sum reduce ---
    float e[4];
    float sum = 0.f;
#pragma unroll
    for (int k = 0; k < 4; ++k) { e[k] = expf(sc[k] - m); sum += e[k]; }
#pragma unroll
    for (int off = 32; off > 0; off >>= 1) sum += __shfl_xor(sum, off);
    __syncthreads();
    if ((tid & 63) == 0) red[4 + (tid >> 6)] = sum;
    __syncthreads();
    float total = red[4] + red[5] + red[6] + red[7];
    float inv = 1.f / total;

#pragma unroll
    for (int k = 0; k < 4; ++k) {
        int s = k * 256 + tid;
        attn[(size_t)s * BSZ + b] = e[k] * inv;
    }
}

// ---------------------------------------------------------------------------
// ctx[b][c] = sum_s attn[s][b] * hids[s][b][c]  (atomic partial over s-chunks)
// grid (BSZ, 8); 256 threads each own 4 consecutive c via float4.
// ---------------------------------------------------------------------------
__global__ __launch_bounds__(256)
void ctx_kernel(const float* __restrict__ hids, const float* __restrict__ attn,
                float* __restrict__ ctx)
{
    const int b   = blockIdx.x;
    const int s0  = blockIdx.y * (SRC_LEN / 8);
    const int tid = threadIdx.x;

    float4 acc = make_float4(0.f, 0.f, 0.f, 0.f);
    for (int s = s0; s < s0 + SRC_LEN / 8; ++s) {
        float w = attn[(size_t)s * BSZ + b];
        if (w != 0.f) {   // masked rows are exactly 0 — skip their 4KB read
            float4 h = *reinterpret_cast<const float4*>(
                &hids[((size_t)s * BSZ + b) * CDIM + tid * 4]);
            acc.x = fmaf(w, h.x, acc.x);
            acc.y = fmaf(w, h.y, acc.y);
            acc.z = fmaf(w, h.z, acc.z);
            acc.w = fmaf(w, h.w, acc.w);
        }
    }
    float* dst = &ctx[(size_t)b * CDIM + tid * 4];
    atomicAdd(dst + 0, acc.x);
    atomicAdd(dst + 1, acc.y);
    atomicAdd(dst + 2, acc.z);
    atomicAdd(dst + 3, acc.w);
}

// ---------------------------------------------------------------------------
extern "C" void kernel_launch(void* const* d_in, const int* in_sizes, int n_in,
                              void* d_out, int out_size, void* d_ws, size_t ws_size,
                              hipStream_t stream)
{
    const float* dsr   = (const float*)d_in[0];  // decoder_state [64][1024]
    const float* hids  = (const float*)d_in[1];  // source_hids [1024][64][1024]
    const int*   lens  = (const int*)  d_in[2];  // src_lengths [64]
    const float* W_enc = (const float*)d_in[3];  // [1024][1024]
    const float* b_enc = (const float*)d_in[4];  // [1024]
    const float* W_dec = (const float*)d_in[5];  // [1024][1024]
    const float* b_dec = (const float*)d_in[6];  // [1024]
    const float* v     = (const float*)d_in[7];  // [1024]

    float* out  = (float*)d_out;
    float* ctx  = out;                      // [64*1024]
    float* attn = out + BSZ * CDIM;         // [1024*64] — scores, then probs
    float* dec  = (float*)d_ws;             // [64*1024] scratch

    // zero ctx (atomic accum) and scores (atomic accum) every call
    hipMemsetAsync(d_out, 0, (size_t)(BSZ * CDIM + SRC_LEN * BSZ) * sizeof(float), stream);

    // dec = decoder_state @ W_dec^T + b_dec
    gemm_kernel<0><<<dim3(1, ADIM / 64), 256, 0, stream>>>(dsr, W_dec, b_dec, nullptr, nullptr, dec);

    // scores[s*B+b] = sum_a tanh(enc + b_enc + dec) * v   (fused, atomic)
    gemm_kernel<1><<<dim3(SRC_LEN * BSZ / 64, ADIM / 64), 256, 0, stream>>>(
        hids, W_enc, b_enc, dec, v, attn);

    // masked softmax over s per column b (in place)
    softmax_kernel<<<BSZ, 256, 0, stream>>>(lens, attn);

    // ctx = sum_s attn * hids
    ctx_kernel<<<dim3(BSZ, 8), 256, 0, stream>>>(hids, attn, ctx);
}

// Round 2
// 715.565 us; speedup vs baseline: 2.9041x; 2.9041x over previous
//
#include <hip/hip_runtime.h>
#include <math.h>

#define SRC_LEN  1024
#define BSZ      64
#define CDIM     1024
#define ADIM     1024
#define KDIM     1024
#define NEG_MASK -1000000.0f

typedef _Float16 f16x8 __attribute__((ext_vector_type(8)));
typedef _Float16 f16x4 __attribute__((ext_vector_type(4)));
typedef float    f32x4 __attribute__((ext_vector_type(4)));

__device__ __forceinline__ float fast_tanh(float x) {
    // tanh(x) = 1 - 2/(exp(2x)+1); exp overflow/underflow saturates correctly.
    float e = __expf(2.0f * x);
    return 1.0f - 2.0f / (e + 1.0f);
}

// ---------------------------------------------------------------------------
// W_enc fp32 -> fp16, 4 elements/thread
// ---------------------------------------------------------------------------
__global__ __launch_bounds__(256)
void convert_kernel(const float* __restrict__ in, _Float16* __restrict__ out)
{
    int i = blockIdx.x * 256 + threadIdx.x;
    float4 x = reinterpret_cast<const float4*>(in)[i];
    f16x4 o;
    o[0] = (_Float16)x.x; o[1] = (_Float16)x.y;
    o[2] = (_Float16)x.z; o[3] = (_Float16)x.w;
    *reinterpret_cast<f16x4*>(&out[(size_t)i * 4]) = o;
}

// ---------------------------------------------------------------------------
// decb[b][n] = decoder_state @ W_dec^T + b_dec + b_enc   (fp32, M=64 tiny)
// one 64-wide n-tile per block
// ---------------------------------------------------------------------------
__global__ __launch_bounds__(256)
void dec_kernel(const float* __restrict__ A, const float* __restrict__ W,
                const float* __restrict__ b1, const float* __restrict__ b2,
                float* __restrict__ out)
{
    const int n0  = blockIdx.x * 64;
    const int tid = threadIdx.x;
    const int tx  = tid & 15;
    const int ty  = tid >> 4;

    __shared__ float Asl[16][64];
    __shared__ float Bsl[16][64];

    float acc[4][4];
#pragma unroll
    for (int i = 0; i < 4; ++i)
#pragma unroll
        for (int j = 0; j < 4; ++j) acc[i][j] = 0.f;

    const int lr = tid >> 2;        // 0..63
    const int lk = (tid & 3) * 4;

    for (int kb = 0; kb < KDIM; kb += 16) {
        float4 a4 = *reinterpret_cast<const float4*>(&A[(size_t)lr * KDIM + kb + lk]);
        float4 b4 = *reinterpret_cast<const float4*>(&W[(size_t)(n0 + lr) * KDIM + kb + lk]);
        __syncthreads();
        Asl[lk + 0][lr] = a4.x; Asl[lk + 1][lr] = a4.y;
        Asl[lk + 2][lr] = a4.z; Asl[lk + 3][lr] = a4.w;
        Bsl[lk + 0][lr] = b4.x; Bsl[lk + 1][lr] = b4.y;
        Bsl[lk + 2][lr] = b4.z; Bsl[lk + 3][lr] = b4.w;
        __syncthreads();
#pragma unroll
        for (int k = 0; k < 16; ++k) {
            float4 av = *reinterpret_cast<const float4*>(&Asl[k][ty * 4]);
            float4 bv = *reinterpret_cast<const float4*>(&Bsl[k][tx * 4]);
            float am[4] = {av.x, av.y, av.z, av.w};
            float bn[4] = {bv.x, bv.y, bv.z, bv.w};
#pragma unroll
            for (int i = 0; i < 4; ++i)
#pragma unroll
                for (int j = 0; j < 4; ++j)
                    acc[i][j] = fmaf(am[i], bn[j], acc[i][j]);
        }
    }
#pragma unroll
    for (int i = 0; i < 4; ++i) {
        int m = ty * 4 + i;
#pragma unroll
        for (int j = 0; j < 4; ++j) {
            int n = n0 + tx * 4 + j;
            out[(size_t)m * ADIM + n] = acc[i][j] + b1[n] + b2[n];
        }
    }
}

// ---------------------------------------------------------------------------
// Fused enc-projection + tanh + v-dot. fp16 MFMA 16x16x32.
// 128x128 tile, BK=64, 4 waves (2x2), 4x4 fragments/wave.
// scores[m] += sum_n tanh(A@W^T + decb[m&63][n]) * v[n]   (atomicAdd)
// ---------------------------------------------------------------------------
__global__ __launch_bounds__(256)
void enc_score_kernel(const float* __restrict__ A,       // [65536][1024] fp32
                      const _Float16* __restrict__ Bw,   // [1024][1024] fp16
                      const float* __restrict__ decb,    // [64][1024] fp32
                      const float* __restrict__ v,       // [1024]
                      float* __restrict__ scores)        // [65536]
{
    const int nb = blockIdx.x;          // 0..7   (n-tiles adjacent -> L3 reuse of A)
    const int mb = blockIdx.y;          // 0..511
    const int m0 = mb * 128, n0 = nb * 128;
    const int tid  = threadIdx.x;
    const int lane = tid & 63;
    const int wid  = tid >> 6;
    const int wm   = wid >> 1, wn = wid & 1;
    const int lc   = lane & 15, g = lane >> 4;

    __shared__ __align__(16) _Float16 As[128 * 64];
    __shared__ __align__(16) _Float16 Bs[128 * 64];

    // staging assignment: thread -> (row, k-half)
    const int srow = tid >> 1;            // 0..127
    const int scol = (tid & 1) * 32;      // element offset in k
    const int sw   = (srow & 7) << 3;     // halfword XOR swizzle

    f32x4 acc[4][4];
#pragma unroll
    for (int i = 0; i < 4; ++i)
#pragma unroll
        for (int j = 0; j < 4; ++j) acc[i][j] = (f32x4){0.f, 0.f, 0.f, 0.f};

    const float*    Aptr = A  + (size_t)(m0 + srow) * KDIM + scol;
    const _Float16* Bptr = Bw + (size_t)(n0 + srow) * KDIM + scol;

    float4 aR[8];
    uint4  bR[4];
#pragma unroll
    for (int i = 0; i < 8; ++i) aR[i] = reinterpret_cast<const float4*>(Aptr)[i];
#pragma unroll
    for (int i = 0; i < 4; ++i) bR[i] = reinterpret_cast<const uint4*>(Bptr)[i];

    for (int kb = 0; kb < KDIM; kb += 64) {
        __syncthreads();   // previous iteration's LDS reads complete
#pragma unroll
        for (int w = 0; w < 4; ++w) {
            float4 x = aR[2 * w], y = aR[2 * w + 1];
            f16x8 p;
            p[0] = (_Float16)x.x; p[1] = (_Float16)x.y;
            p[2] = (_Float16)x.z; p[3] = (_Float16)x.w;
            p[4] = (_Float16)y.x; p[5] = (_Float16)y.y;
            p[6] = (_Float16)y.z; p[7] = (_Float16)y.w;
            int hw = (srow * 64 + scol + 8 * w) ^ sw;
            *reinterpret_cast<f16x8*>(&As[hw]) = p;
            *reinterpret_cast<uint4*>(&Bs[hw]) = bR[w];
        }
        __syncthreads();
        if (kb + 64 < KDIM) {
#pragma unroll
            for (int i = 0; i < 8; ++i)
                aR[i] = reinterpret_cast<const float4*>(Aptr + kb + 64)[i];
#pragma unroll
            for (int i = 0; i < 4; ++i)
                bR[i] = reinterpret_cast<const uint4*>(Bptr + kb + 64)[i];
        }
#pragma unroll
        for (int ks = 0; ks < 2; ++ks) {
            f16x8 af[4], bf[4];
#pragma unroll
            for (int mi = 0; mi < 4; ++mi) {
                int r  = wm * 64 + mi * 16 + lc;
                int hw = (r * 64 + ks * 32 + g * 8) ^ ((r & 7) << 3);
                af[mi] = *reinterpret_cast<const f16x8*>(&As[hw]);
            }
#pragma unroll
            for (int ni = 0; ni < 4; ++ni) {
                int r  = wn * 64 + ni * 16 + lc;
                int hw = (r * 64 + ks * 32 + g * 8) ^ ((r & 7) << 3);
                bf[ni] = *reinterpret_cast<const f16x8*>(&Bs[hw]);
            }
#pragma unroll
            for (int mi = 0; mi < 4; ++mi)
#pragma unroll
                for (int ni = 0; ni < 4; ++ni)
                    acc[mi][ni] = __builtin_amdgcn_mfma_f32_16x16x32_f16(
                        af[mi], bf[ni], acc[mi][ni], 0, 0, 0);
        }
    }

    // ---- fused epilogue: tanh + v-dot + row reduce ----
    __syncthreads();   // done with As/Bs as f16 tiles

    float psum[4][4];  // [mi][r]
#pragma unroll
    for (int mi = 0; mi < 4; ++mi)
#pragma unroll
        for (int r = 0; r < 4; ++r) psum[mi][r] = 0.f;

#pragma unroll
    for (int mi = 0; mi < 4; ++mi) {
#pragma unroll
        for (int ni = 0; ni < 4; ++ni) {
            int n = n0 + wn * 64 + ni * 16 + lc;
            float vn = v[n];
#pragma unroll
            for (int r = 0; r < 4; ++r) {
                int b = mi * 16 + g * 4 + r;          // (m & 63)
                float x = acc[mi][ni][r] + decb[(size_t)b * ADIM + n];
                psum[mi][r] = fmaf(fast_tanh(x), vn, psum[mi][r]);
            }
        }
    }
    // reduce over the 16 lanes of each g-group (cols)
#pragma unroll
    for (int mi = 0; mi < 4; ++mi)
#pragma unroll
        for (int r = 0; r < 4; ++r) {
            float s = psum[mi][r];
            s += __shfl_xor(s, 1);
            s += __shfl_xor(s, 2);
            s += __shfl_xor(s, 4);
            s += __shfl_xor(s, 8);
            psum[mi][r] = s;
        }

    float* red = reinterpret_cast<float*>(As);   // [128][2]
    if (lc == 0) {
#pragma unroll
        for (int mi = 0; mi < 4; ++mi)
#pragma unroll
            for (int r = 0; r < 4; ++r) {
                int row = wm * 64 + mi * 16 + g * 4 + r;
                red[row * 2 + wn] = psum[mi][r];
            }
    }
    __syncthreads();
    if (tid < 128)
        atomicAdd(&scores[m0 + tid], red[tid * 2] + red[tid * 2 + 1]);
}

// ---------------------------------------------------------------------------
// Masked softmax over S per batch column, in place. One block per b.
// ---------------------------------------------------------------------------
__global__ __launch_bounds__(256)
void softmax_kernel(const int* __restrict__ lens, float* __restrict__ attn)
{
    const int b   = blockIdx.x;
    const int tid = threadIdx.x;
    const int len = lens[b];

    float sc[4];
#pragma unroll
    for (int k = 0; k < 4; ++k) {
        int s = k * 256 + tid;
        float x = attn[(size_t)s * BSZ + b];
        sc[k] = (s < len) ? x : NEG_MASK;
    }

    __shared__ float red[8];

    float m = fmaxf(fmaxf(sc[0], sc[1]), fmaxf(sc[2], sc[3]));
#pragma unroll
    for (int off = 32; off > 0; off >>= 1) m = fmaxf(m, __shfl_xor(m, off));
    if ((tid & 63) == 0) red[tid >> 6] = m;
    __syncthreads();
    m = fmaxf(fmaxf(red[0], red[1]), fmaxf(red[2], red[3]));

    float e[4];
    float sum = 0.f;
#pragma unroll
    for (int k = 0; k < 4; ++k) { e[k] = expf(sc[k] - m); sum += e[k]; }
#pragma unroll
    for (int off = 32; off > 0; off >>= 1) sum += __shfl_xor(sum, off);
    __syncthreads();
    if ((tid & 63) == 0) red[4 + (tid >> 6)] = sum;
    __syncthreads();
    float total = red[4] + red[5] + red[6] + red[7];
    float inv = 1.f / total;

#pragma unroll
    for (int k = 0; k < 4; ++k) {
        int s = k * 256 + tid;
        attn[(size_t)s * BSZ + b] = e[k] * inv;
    }
}

// ---------------------------------------------------------------------------
// ctx[b][c] = sum_s attn[s][b] * hids[s][b][c]
// ---------------------------------------------------------------------------
__global__ __launch_bounds__(256)
void ctx_kernel(const float* __restrict__ hids, const float* __restrict__ attn,
                float* __restrict__ ctx)
{
    const int b   = blockIdx.x;
    const int s0  = blockIdx.y * (SRC_LEN / 8);
    const int tid = threadIdx.x;

    float4 acc = make_float4(0.f, 0.f, 0.f, 0.f);
    for (int s = s0; s < s0 + SRC_LEN / 8; ++s) {
        float w = attn[(size_t)s * BSZ + b];
        if (w != 0.f) {
            float4 h = *reinterpret_cast<const float4*>(
                &hids[((size_t)s * BSZ + b) * CDIM + tid * 4]);
            acc.x = fmaf(w, h.x, acc.x);
            acc.y = fmaf(w, h.y, acc.y);
            acc.z = fmaf(w, h.z, acc.z);
            acc.w = fmaf(w, h.w, acc.w);
        }
    }
    float* dst = &ctx[(size_t)b * CDIM + tid * 4];
    atomicAdd(dst + 0, acc.x);
    atomicAdd(dst + 1, acc.y);
    atomicAdd(dst + 2, acc.z);
    atomicAdd(dst + 3, acc.w);
}

// ---------------------------------------------------------------------------
extern "C" void kernel_launch(void* const* d_in, const int* in_sizes, int n_in,
                              void* d_out, int out_size, void* d_ws, size_t ws_size,
                              hipStream_t stream)
{
    const float* dsr   = (const float*)d_in[0];
    const float* hids  = (const float*)d_in[1];
    const int*   lens  = (const int*)  d_in[2];
    const float* W_enc = (const float*)d_in[3];
    const float* b_enc = (const float*)d_in[4];
    const float* W_dec = (const float*)d_in[5];
    const float* b_dec = (const float*)d_in[6];
    const float* v     = (const float*)d_in[7];

    float* out  = (float*)d_out;
    float* ctx  = out;                       // [64*1024]
    float* attn = out + BSZ * CDIM;          // [1024*64] scores -> probs

    float*     decb = (float*)d_ws;                                   // 256 KB
    _Float16*  Wf16 = (_Float16*)((char*)d_ws + (size_t)BSZ * ADIM * 4); // 2 MB

    hipMemsetAsync(d_out, 0, (size_t)(BSZ * CDIM + SRC_LEN * BSZ) * sizeof(float), stream);

    convert_kernel<<<ADIM * KDIM / 4 / 256, 256, 0, stream>>>(W_enc, Wf16);
    dec_kernel<<<ADIM / 64, 256, 0, stream>>>(dsr, W_dec, b_dec, b_enc, decb);
    enc_score_kernel<<<dim3(8, 512), 256, 0, stream>>>(hids, Wf16, decb, v, attn);
    softmax_kernel<<<BSZ, 256, 0, stream>>>(lens, attn);
    ctx_kernel<<<dim3(BSZ, 8), 256, 0, stream>>>(hids, attn, ctx);
}

// Round 3
// 666.648 us; speedup vs baseline: 3.1172x; 1.0734x over previous
//
#include <hip/hip_runtime.h>
#include <math.h>

#define SRC_LEN  1024
#define BSZ      64
#define CDIM     1024
#define ADIM     1024
#define KDIM     1024
#define NEG_MASK -1000000.0f

typedef _Float16 f16x8 __attribute__((ext_vector_type(8)));
typedef _Float16 f16x4 __attribute__((ext_vector_type(4)));
typedef float    f32x4 __attribute__((ext_vector_type(4)));

__device__ __forceinline__ float fast_tanh(float x) {
    float e = __expf(2.0f * x);
    return 1.0f - 2.0f / (e + 1.0f);
}

// ---------------------------------------------------------------------------
// W_enc fp32 -> fp16, 4 elements/thread
// ---------------------------------------------------------------------------
__global__ __launch_bounds__(256)
void convert_kernel(const float* __restrict__ in, _Float16* __restrict__ out)
{
    int i = blockIdx.x * 256 + threadIdx.x;
    float4 x = reinterpret_cast<const float4*>(in)[i];
    f16x4 o;
    o[0] = (_Float16)x.x; o[1] = (_Float16)x.y;
    o[2] = (_Float16)x.z; o[3] = (_Float16)x.w;
    *reinterpret_cast<f16x4*>(&out[(size_t)i * 4]) = o;
}

// ---------------------------------------------------------------------------
// decb[b][n] = decoder_state @ W_dec^T + b_dec + b_enc   (fp32, M=64 tiny)
// ---------------------------------------------------------------------------
__global__ __launch_bounds__(256)
void dec_kernel(const float* __restrict__ A, const float* __restrict__ W,
                const float* __restrict__ b1, const float* __restrict__ b2,
                float* __restrict__ out)
{
    const int n0  = blockIdx.x * 64;
    const int tid = threadIdx.x;
    const int tx  = tid & 15;
    const int ty  = tid >> 4;

    __shared__ float Asl[16][64];
    __shared__ float Bsl[16][64];

    float acc[4][4];
#pragma unroll
    for (int i = 0; i < 4; ++i)
#pragma unroll
        for (int j = 0; j < 4; ++j) acc[i][j] = 0.f;

    const int lr = tid >> 2;
    const int lk = (tid & 3) * 4;

    for (int kb = 0; kb < KDIM; kb += 16) {
        float4 a4 = *reinterpret_cast<const float4*>(&A[(size_t)lr * KDIM + kb + lk]);
        float4 b4 = *reinterpret_cast<const float4*>(&W[(size_t)(n0 + lr) * KDIM + kb + lk]);
        __syncthreads();
        Asl[lk + 0][lr] = a4.x; Asl[lk + 1][lr] = a4.y;
        Asl[lk + 2][lr] = a4.z; Asl[lk + 3][lr] = a4.w;
        Bsl[lk + 0][lr] = b4.x; Bsl[lk + 1][lr] = b4.y;
        Bsl[lk + 2][lr] = b4.z; Bsl[lk + 3][lr] = b4.w;
        __syncthreads();
#pragma unroll
        for (int k = 0; k < 16; ++k) {
            float4 av = *reinterpret_cast<const float4*>(&Asl[k][ty * 4]);
            float4 bv = *reinterpret_cast<const float4*>(&Bsl[k][tx * 4]);
            float am[4] = {av.x, av.y, av.z, av.w};
            float bn[4] = {bv.x, bv.y, bv.z, bv.w};
#pragma unroll
            for (int i = 0; i < 4; ++i)
#pragma unroll
                for (int j = 0; j < 4; ++j)
                    acc[i][j] = fmaf(am[i], bn[j], acc[i][j]);
        }
    }
#pragma unroll
    for (int i = 0; i < 4; ++i) {
        int m = ty * 4 + i;
#pragma unroll
        for (int j = 0; j < 4; ++j) {
            int n = n0 + tx * 4 + j;
            out[(size_t)m * ADIM + n] = acc[i][j] + b1[n] + b2[n];
        }
    }
}

// ---------------------------------------------------------------------------
// Fused enc-projection + tanh + v-dot. fp16 MFMA 16x16x32.
// 128x128 tile, BK=64, 4 waves (2x2), 4x4 fragments/wave.
// Flat grid 4096, XCD-grouped: all 8 nb-blocks of one mb share an XCD
// so the 512KB A-panel is served from that XCD's L2 after first touch.
// ---------------------------------------------------------------------------
__global__ __launch_bounds__(256)
void enc_score_kernel(const float* __restrict__ A,       // [65536][1024] fp32
                      const _Float16* __restrict__ Bw,   // [1024][1024] fp16
                      const float* __restrict__ decb,    // [64][1024] fp32
                      const float* __restrict__ v,       // [1024]
                      float* __restrict__ scores)        // [65536]
{
    // bid layout: bid = (mb&7) + nb*8 + (mb>>3)*64
    // => XCD(bid)=bid%8=mb%8 : the 8 nb-sharers co-reside on one XCD.
    const int bid = blockIdx.x;
    const int nb  = (bid >> 3) & 7;
    const int mb  = (bid & 7) + ((bid >> 6) << 3);
    const int m0 = mb * 128, n0 = nb * 128;
    const int tid  = threadIdx.x;
    const int lane = tid & 63;
    const int wid  = tid >> 6;
    const int wm   = wid >> 1, wn = wid & 1;
    const int lc   = lane & 15, g = lane >> 4;

    __shared__ __align__(16) _Float16 As[128 * 64];
    __shared__ __align__(16) _Float16 Bs[128 * 64];

    const int srow = tid >> 1;            // 0..127
    const int scol = (tid & 1) * 32;      // element offset in k
    const int sw   = (srow & 7) << 3;     // halfword XOR swizzle

    f32x4 acc[4][4];
#pragma unroll
    for (int i = 0; i < 4; ++i)
#pragma unroll
        for (int j = 0; j < 4; ++j) acc[i][j] = (f32x4){0.f, 0.f, 0.f, 0.f};

    const float*    Aptr = A  + (size_t)(m0 + srow) * KDIM + scol;
    const _Float16* Bptr = Bw + (size_t)(n0 + srow) * KDIM + scol;

    float4 aR[8];
    uint4  bR[4];
#pragma unroll
    for (int i = 0; i < 8; ++i) aR[i] = reinterpret_cast<const float4*>(Aptr)[i];
#pragma unroll
    for (int i = 0; i < 4; ++i) bR[i] = reinterpret_cast<const uint4*>(Bptr)[i];

    for (int kb = 0; kb < KDIM; kb += 64) {
        __syncthreads();
#pragma unroll
        for (int w = 0; w < 4; ++w) {
            float4 x = aR[2 * w], y = aR[2 * w + 1];
            f16x8 p;
            p[0] = (_Float16)x.x; p[1] = (_Float16)x.y;
            p[2] = (_Float16)x.z; p[3] = (_Float16)x.w;
            p[4] = (_Float16)y.x; p[5] = (_Float16)y.y;
            p[6] = (_Float16)y.z; p[7] = (_Float16)y.w;
            int hw = (srow * 64 + scol + 8 * w) ^ sw;
            *reinterpret_cast<f16x8*>(&As[hw]) = p;
            *reinterpret_cast<uint4*>(&Bs[hw]) = bR[w];
        }
        __syncthreads();
        if (kb + 64 < KDIM) {
#pragma unroll
            for (int i = 0; i < 8; ++i)
                aR[i] = reinterpret_cast<const float4*>(Aptr + kb + 64)[i];
#pragma unroll
            for (int i = 0; i < 4; ++i)
                bR[i] = reinterpret_cast<const uint4*>(Bptr + kb + 64)[i];
        }
#pragma unroll
        for (int ks = 0; ks < 2; ++ks) {
            f16x8 af[4], bf[4];
#pragma unroll
            for (int mi = 0; mi < 4; ++mi) {
                int r  = wm * 64 + mi * 16 + lc;
                int hw = (r * 64 + ks * 32 + g * 8) ^ ((r & 7) << 3);
                af[mi] = *reinterpret_cast<const f16x8*>(&As[hw]);
            }
#pragma unroll
            for (int ni = 0; ni < 4; ++ni) {
                int r  = wn * 64 + ni * 16 + lc;
                int hw = (r * 64 + ks * 32 + g * 8) ^ ((r & 7) << 3);
                bf[ni] = *reinterpret_cast<const f16x8*>(&Bs[hw]);
            }
#pragma unroll
            for (int mi = 0; mi < 4; ++mi)
#pragma unroll
                for (int ni = 0; ni < 4; ++ni)
                    acc[mi][ni] = __builtin_amdgcn_mfma_f32_16x16x32_f16(
                        af[mi], bf[ni], acc[mi][ni], 0, 0, 0);
        }
    }

    // ---- fused epilogue: tanh + v-dot + row reduce ----
    __syncthreads();

    float psum[4][4];
#pragma unroll
    for (int mi = 0; mi < 4; ++mi)
#pragma unroll
        for (int r = 0; r < 4; ++r) psum[mi][r] = 0.f;

#pragma unroll
    for (int mi = 0; mi < 4; ++mi) {
#pragma unroll
        for (int ni = 0; ni < 4; ++ni) {
            int n = n0 + wn * 64 + ni * 16 + lc;
            float vn = v[n];
#pragma unroll
            for (int r = 0; r < 4; ++r) {
                int b = mi * 16 + g * 4 + r;
                float x = acc[mi][ni][r] + decb[(size_t)b * ADIM + n];
                psum[mi][r] = fmaf(fast_tanh(x), vn, psum[mi][r]);
            }
        }
    }
#pragma unroll
    for (int mi = 0; mi < 4; ++mi)
#pragma unroll
        for (int r = 0; r < 4; ++r) {
            float s = psum[mi][r];
            s += __shfl_xor(s, 1);
            s += __shfl_xor(s, 2);
            s += __shfl_xor(s, 4);
            s += __shfl_xor(s, 8);
            psum[mi][r] = s;
        }

    float* red = reinterpret_cast<float*>(As);
    if (lc == 0) {
#pragma unroll
        for (int mi = 0; mi < 4; ++mi)
#pragma unroll
            for (int r = 0; r < 4; ++r) {
                int row = wm * 64 + mi * 16 + g * 4 + r;
                red[row * 2 + wn] = psum[mi][r];
            }
    }
    __syncthreads();
    if (tid < 128)
        atomicAdd(&scores[m0 + tid], red[tid * 2] + red[tid * 2 + 1]);
}

// ---------------------------------------------------------------------------
// Masked softmax over S per batch column, in place. One block per b.
// ---------------------------------------------------------------------------
__global__ __launch_bounds__(256)
void softmax_kernel(const int* __restrict__ lens, float* __restrict__ attn)
{
    const int b   = blockIdx.x;
    const int tid = threadIdx.x;
    const int len = lens[b];

    float sc[4];
#pragma unroll
    for (int k = 0; k < 4; ++k) {
        int s = k * 256 + tid;
        float x = attn[(size_t)s * BSZ + b];
        sc[k] = (s < len) ? x : NEG_MASK;
    }

    __shared__ float red[8];

    float m = fmaxf(fmaxf(sc[0], sc[1]), fmaxf(sc[2], sc[3]));
#pragma unroll
    for (int off = 32; off > 0; off >>= 1) m = fmaxf(m, __shfl_xor(m, off));
    if ((tid & 63) == 0) red[tid >> 6] = m;
    __syncthreads();
    m = fmaxf(fmaxf(red[0], red[1]), fmaxf(red[2], red[3]));

    float e[4];
    float sum = 0.f;
#pragma unroll
    for (int k = 0; k < 4; ++k) { e[k] = expf(sc[k] - m); sum += e[k]; }
#pragma unroll
    for (int off = 32; off > 0; off >>= 1) sum += __shfl_xor(sum, off);
    __syncthreads();
    if ((tid & 63) == 0) red[4 + (tid >> 6)] = sum;
    __syncthreads();
    float total = red[4] + red[5] + red[6] + red[7];
    float inv = 1.f / total;

#pragma unroll
    for (int k = 0; k < 4; ++k) {
        int s = k * 256 + tid;
        attn[(size_t)s * BSZ + b] = e[k] * inv;
    }
}

// ---------------------------------------------------------------------------
// ctx[b][c] = sum_s attn[s][b] * hids[s][b][c]
// ---------------------------------------------------------------------------
__global__ __launch_bounds__(256)
void ctx_kernel(const float* __restrict__ hids, const float* __restrict__ attn,
                float* __restrict__ ctx)
{
    const int b   = blockIdx.x;
    const int s0  = blockIdx.y * (SRC_LEN / 8);
    const int tid = threadIdx.x;

    float4 acc = make_float4(0.f, 0.f, 0.f, 0.f);
    for (int s = s0; s < s0 + SRC_LEN / 8; ++s) {
        float w = attn[(size_t)s * BSZ + b];
        if (w != 0.f) {
            float4 h = *reinterpret_cast<const float4*>(
                &hids[((size_t)s * BSZ + b) * CDIM + tid * 4]);
            acc.x = fmaf(w, h.x, acc.x);
            acc.y = fmaf(w, h.y, acc.y);
            acc.z = fmaf(w, h.z, acc.z);
            acc.w = fmaf(w, h.w, acc.w);
        }
    }
    float* dst = &ctx[(size_t)b * CDIM + tid * 4];
    atomicAdd(dst + 0, acc.x);
    atomicAdd(dst + 1, acc.y);
    atomicAdd(dst + 2, acc.z);
    atomicAdd(dst + 3, acc.w);
}

// ---------------------------------------------------------------------------
extern "C" void kernel_launch(void* const* d_in, const int* in_sizes, int n_in,
                              void* d_out, int out_size, void* d_ws, size_t ws_size,
                              hipStream_t stream)
{
    const float* dsr   = (const float*)d_in[0];
    const float* hids  = (const float*)d_in[1];
    const int*   lens  = (const int*)  d_in[2];
    const float* W_enc = (const float*)d_in[3];
    const float* b_enc = (const float*)d_in[4];
    const float* W_dec = (const float*)d_in[5];
    const float* b_dec = (const float*)d_in[6];
    const float* v     = (const float*)d_in[7];

    float* out  = (float*)d_out;
    float* ctx  = out;                       // [64*1024]
    float* attn = out + BSZ * CDIM;          // [1024*64] scores -> probs

    float*     decb = (float*)d_ws;                                      // 256 KB
    _Float16*  Wf16 = (_Float16*)((char*)d_ws + (size_t)BSZ * ADIM * 4); // 2 MB

    hipMemsetAsync(d_out, 0, (size_t)(BSZ * CDIM + SRC_LEN * BSZ) * sizeof(float), stream);

    convert_kernel<<<ADIM * KDIM / 4 / 256, 256, 0, stream>>>(W_enc, Wf16);
    dec_kernel<<<ADIM / 64, 256, 0, stream>>>(dsr, W_dec, b_dec, b_enc, decb);
    enc_score_kernel<<<4096, 256, 0, stream>>>(hids, Wf16, decb, v, attn);
    softmax_kernel<<<BSZ, 256, 0, stream>>>(lens, attn);
    ctx_kernel<<<dim3(BSZ, 8), 256, 0, stream>>>(hids, attn, ctx);
}

// Round 4
// 432.671 us; speedup vs baseline: 4.8029x; 1.5408x over previous
//
#include <hip/hip_runtime.h>
#include <math.h>

#define SRC_LEN  1024
#define BSZ      64
#define CDIM     1024
#define ADIM     1024
#define KDIM     1024
#define MROWS    (SRC_LEN * BSZ)
#define NEG_MASK -1000000.0f

typedef _Float16 f16x8 __attribute__((ext_vector_type(8)));
typedef _Float16 f16x4 __attribute__((ext_vector_type(4)));
typedef float    f32x4 __attribute__((ext_vector_type(4)));

__device__ __forceinline__ float fast_tanh(float x) {
    float e = __expf(2.0f * x);
    return 1.0f - 2.0f / (e + 1.0f);
}

// async global(16B) -> LDS, per-lane global src, wave-uniform LDS base
__device__ __forceinline__ void gload16(const _Float16* g, _Float16* l) {
    __builtin_amdgcn_global_load_lds(
        (const __attribute__((address_space(1))) unsigned int*)g,
        (__attribute__((address_space(3))) unsigned int*)l, 16, 0, 0);
}

// ---------------------------------------------------------------------------
// fp32 -> fp16, 8 elements/thread
// ---------------------------------------------------------------------------
__global__ __launch_bounds__(256)
void convert8_kernel(const float* __restrict__ in, _Float16* __restrict__ out)
{
    size_t i = ((size_t)blockIdx.x * 256 + threadIdx.x) * 8;
    float4 x = *reinterpret_cast<const float4*>(in + i);
    float4 y = *reinterpret_cast<const float4*>(in + i + 4);
    f16x8 o;
    o[0] = (_Float16)x.x; o[1] = (_Float16)x.y;
    o[2] = (_Float16)x.z; o[3] = (_Float16)x.w;
    o[4] = (_Float16)y.x; o[5] = (_Float16)y.y;
    o[6] = (_Float16)y.z; o[7] = (_Float16)y.w;
    *reinterpret_cast<f16x8*>(out + i) = o;
}

// ---------------------------------------------------------------------------
// decb[b][n] = decoder_state @ W_dec^T + b_dec + b_enc   (fp32, exact-ish)
// ---------------------------------------------------------------------------
__global__ __launch_bounds__(256)
void dec_kernel(const float* __restrict__ A, const float* __restrict__ W,
                const float* __restrict__ b1, const float* __restrict__ b2,
                float* __restrict__ out)
{
    const int n0  = blockIdx.x * 64;
    const int tid = threadIdx.x;
    const int tx  = tid & 15;
    const int ty  = tid >> 4;

    __shared__ float Asl[16][64];
    __shared__ float Bsl[16][64];

    float acc[4][4];
#pragma unroll
    for (int i = 0; i < 4; ++i)
#pragma unroll
        for (int j = 0; j < 4; ++j) acc[i][j] = 0.f;

    const int lr = tid >> 2;
    const int lk = (tid & 3) * 4;

    for (int kb = 0; kb < KDIM; kb += 16) {
        float4 a4 = *reinterpret_cast<const float4*>(&A[(size_t)lr * KDIM + kb + lk]);
        float4 b4 = *reinterpret_cast<const float4*>(&W[(size_t)(n0 + lr) * KDIM + kb + lk]);
        __syncthreads();
        Asl[lk + 0][lr] = a4.x; Asl[lk + 1][lr] = a4.y;
        Asl[lk + 2][lr] = a4.z; Asl[lk + 3][lr] = a4.w;
        Bsl[lk + 0][lr] = b4.x; Bsl[lk + 1][lr] = b4.y;
        Bsl[lk + 2][lr] = b4.z; Bsl[lk + 3][lr] = b4.w;
        __syncthreads();
#pragma unroll
        for (int k = 0; k < 16; ++k) {
            float4 av = *reinterpret_cast<const float4*>(&Asl[k][ty * 4]);
            float4 bv = *reinterpret_cast<const float4*>(&Bsl[k][tx * 4]);
            float am[4] = {av.x, av.y, av.z, av.w};
            float bn[4] = {bv.x, bv.y, bv.z, bv.w};
#pragma unroll
            for (int i = 0; i < 4; ++i)
#pragma unroll
                for (int j = 0; j < 4; ++j)
                    acc[i][j] = fmaf(am[i], bn[j], acc[i][j]);
        }
    }
#pragma unroll
    for (int i = 0; i < 4; ++i) {
        int m = ty * 4 + i;
#pragma unroll
        for (int j = 0; j < 4; ++j) {
            int n = n0 + tx * 4 + j;
            out[(size_t)m * ADIM + n] = acc[i][j] + b1[n] + b2[n];
        }
    }
}

// ---------------------------------------------------------------------------
// FAST PATH: fused enc-projection + tanh + v-dot, m97 structure.
// 128x128 tile, BK=64, 4 waves (2x2), global_load_lds(16B) for A and B,
// linear LDS, 2-barrier K-loop. XCD-grouped bid decode (A-panel L2 reuse).
// ---------------------------------------------------------------------------
__global__ __launch_bounds__(256)
void enc_score_direct(const _Float16* __restrict__ A16,  // [65536][1024]
                      const _Float16* __restrict__ Bw,   // [1024][1024]
                      const float* __restrict__ decb,    // [64][1024]
                      const float* __restrict__ v,       // [1024]
                      float* __restrict__ scores)        // [65536]
{
    const int bid = blockIdx.x;
    const int nb  = (bid >> 3) & 7;
    const int mb  = (bid & 7) + ((bid >> 6) << 3);
    const int m0 = mb * 128, n0 = nb * 128;
    const int tid  = threadIdx.x;
    const int lane = tid & 63;
    const int wid  = tid >> 6;
    const int wm   = wid >> 1, wn = wid & 1;
    const int lc   = lane & 15, g = lane >> 4;

    __shared__ __align__(16) _Float16 As[128 * 64];
    __shared__ __align__(16) _Float16 Bs[128 * 64];

    // staging: instr (wid,i) covers 8 rows; lane -> (row lane>>3, col (lane&7)*8)
    const int rL = lane >> 3;
    const int cL = (lane & 7) * 8;

    f32x4 acc[4][4];
#pragma unroll
    for (int i = 0; i < 4; ++i)
#pragma unroll
        for (int j = 0; j < 4; ++j) acc[i][j] = (f32x4){0.f, 0.f, 0.f, 0.f};

    const _Float16* Ag = A16 + (size_t)m0 * KDIM;
    const _Float16* Bg = Bw  + (size_t)n0 * KDIM;

    for (int kb = 0; kb < KDIM; kb += 64) {
        __syncthreads();   // all waves done reading previous tile
#pragma unroll
        for (int i = 0; i < 4; ++i) {
            int chunk = wid * 4 + i;            // 0..15 (8 rows each)
            int row   = chunk * 8 + rL;         // 0..127
            gload16(Ag + (size_t)row * KDIM + kb + cL, &As[chunk * 512]);
            gload16(Bg + (size_t)row * KDIM + kb + cL, &Bs[chunk * 512]);
        }
        asm volatile("s_waitcnt vmcnt(0)" ::: "memory");
        __syncthreads();   // staged tile visible to all waves
#pragma unroll
        for (int ks = 0; ks < 2; ++ks) {
            f16x8 af[4], bf[4];
#pragma unroll
            for (int mi = 0; mi < 4; ++mi) {
                int r = wm * 64 + mi * 16 + lc;
                af[mi] = *reinterpret_cast<const f16x8*>(&As[r * 64 + ks * 32 + g * 8]);
            }
#pragma unroll
            for (int ni = 0; ni < 4; ++ni) {
                int r = wn * 64 + ni * 16 + lc;
                bf[ni] = *reinterpret_cast<const f16x8*>(&Bs[r * 64 + ks * 32 + g * 8]);
            }
#pragma unroll
            for (int mi = 0; mi < 4; ++mi)
#pragma unroll
                for (int ni = 0; ni < 4; ++ni)
                    acc[mi][ni] = __builtin_amdgcn_mfma_f32_16x16x32_f16(
                        af[mi], bf[ni], acc[mi][ni], 0, 0, 0);
        }
    }

    // ---- fused epilogue: tanh + v-dot + row reduce ----
    __syncthreads();

    float psum[4][4];
#pragma unroll
    for (int mi = 0; mi < 4; ++mi)
#pragma unroll
        for (int r = 0; r < 4; ++r) psum[mi][r] = 0.f;

#pragma unroll
    for (int mi = 0; mi < 4; ++mi) {
#pragma unroll
        for (int ni = 0; ni < 4; ++ni) {
            int n = n0 + wn * 64 + ni * 16 + lc;
            float vn = v[n];
#pragma unroll
            for (int r = 0; r < 4; ++r) {
                int b = mi * 16 + g * 4 + r;          // m & 63
                float x = acc[mi][ni][r] + decb[(size_t)b * ADIM + n];
                psum[mi][r] = fmaf(fast_tanh(x), vn, psum[mi][r]);
            }
        }
    }
#pragma unroll
    for (int mi = 0; mi < 4; ++mi)
#pragma unroll
        for (int r = 0; r < 4; ++r) {
            float s = psum[mi][r];
            s += __shfl_xor(s, 1);
            s += __shfl_xor(s, 2);
            s += __shfl_xor(s, 4);
            s += __shfl_xor(s, 8);
            psum[mi][r] = s;
        }

    float* red = reinterpret_cast<float*>(As);   // [128][2]
    if (lc == 0) {
#pragma unroll
        for (int mi = 0; mi < 4; ++mi)
#pragma unroll
            for (int r = 0; r < 4; ++r) {
                int row = wm * 64 + mi * 16 + g * 4 + r;
                red[row * 2 + wn] = psum[mi][r];
            }
    }
    __syncthreads();
    if (tid < 128)
        atomicAdd(&scores[m0 + tid], red[tid * 2] + red[tid * 2 + 1]);
}

// ---------------------------------------------------------------------------
// FALLBACK (ws too small): R3 reg-staged fp32-A version.
// ---------------------------------------------------------------------------
__global__ __launch_bounds__(256)
void enc_score_fallback(const float* __restrict__ A,
                        const _Float16* __restrict__ Bw,
                        const float* __restrict__ decb,
                        const float* __restrict__ v,
                        float* __restrict__ scores)
{
    const int bid = blockIdx.x;
    const int nb  = (bid >> 3) & 7;
    const int mb  = (bid & 7) + ((bid >> 6) << 3);
    const int m0 = mb * 128, n0 = nb * 128;
    const int tid  = threadIdx.x;
    const int lane = tid & 63;
    const int wid  = tid >> 6;
    const int wm   = wid >> 1, wn = wid & 1;
    const int lc   = lane & 15, g = lane >> 4;

    __shared__ __align__(16) _Float16 As[128 * 64];
    __shared__ __align__(16) _Float16 Bs[128 * 64];

    const int srow = tid >> 1;
    const int scol = (tid & 1) * 32;
    const int sw   = (srow & 7) << 3;

    f32x4 acc[4][4];
#pragma unroll
    for (int i = 0; i < 4; ++i)
#pragma unroll
        for (int j = 0; j < 4; ++j) acc[i][j] = (f32x4){0.f, 0.f, 0.f, 0.f};

    const float*    Aptr = A  + (size_t)(m0 + srow) * KDIM + scol;
    const _Float16* Bptr = Bw + (size_t)(n0 + srow) * KDIM + scol;

    float4 aR[8];
    uint4  bR[4];
#pragma unroll
    for (int i = 0; i < 8; ++i) aR[i] = reinterpret_cast<const float4*>(Aptr)[i];
#pragma unroll
    for (int i = 0; i < 4; ++i) bR[i] = reinterpret_cast<const uint4*>(Bptr)[i];

    for (int kb = 0; kb < KDIM; kb += 64) {
        __syncthreads();
#pragma unroll
        for (int w = 0; w < 4; ++w) {
            float4 x = aR[2 * w], y = aR[2 * w + 1];
            f16x8 p;
            p[0] = (_Float16)x.x; p[1] = (_Float16)x.y;
            p[2] = (_Float16)x.z; p[3] = (_Float16)x.w;
            p[4] = (_Float16)y.x; p[5] = (_Float16)y.y;
            p[6] = (_Float16)y.z; p[7] = (_Float16)y.w;
            int hw = (srow * 64 + scol + 8 * w) ^ sw;
            *reinterpret_cast<f16x8*>(&As[hw]) = p;
            *reinterpret_cast<uint4*>(&Bs[hw]) = bR[w];
        }
        __syncthreads();
        if (kb + 64 < KDIM) {
#pragma unroll
            for (int i = 0; i < 8; ++i)
                aR[i] = reinterpret_cast<const float4*>(Aptr + kb + 64)[i];
#pragma unroll
            for (int i = 0; i < 4; ++i)
                bR[i] = reinterpret_cast<const uint4*>(Bptr + kb + 64)[i];
        }
#pragma unroll
        for (int ks = 0; ks < 2; ++ks) {
            f16x8 af[4], bf[4];
#pragma unroll
            for (int mi = 0; mi < 4; ++mi) {
                int r  = wm * 64 + mi * 16 + lc;
                int hw = (r * 64 + ks * 32 + g * 8) ^ ((r & 7) << 3);
                af[mi] = *reinterpret_cast<const f16x8*>(&As[hw]);
            }
#pragma unroll
            for (int ni = 0; ni < 4; ++ni) {
                int r  = wn * 64 + ni * 16 + lc;
                int hw = (r * 64 + ks * 32 + g * 8) ^ ((r & 7) << 3);
                bf[ni] = *reinterpret_cast<const f16x8*>(&Bs[hw]);
            }
#pragma unroll
            for (int mi = 0; mi < 4; ++mi)
#pragma unroll
                for (int ni = 0; ni < 4; ++ni)
                    acc[mi][ni] = __builtin_amdgcn_mfma_f32_16x16x32_f16(
                        af[mi], bf[ni], acc[mi][ni], 0, 0, 0);
        }
    }

    __syncthreads();

    float psum[4][4];
#pragma unroll
    for (int mi = 0; mi < 4; ++mi)
#pragma unroll
        for (int r = 0; r < 4; ++r) psum[mi][r] = 0.f;

#pragma unroll
    for (int mi = 0; mi < 4; ++mi) {
#pragma unroll
        for (int ni = 0; ni < 4; ++ni) {
            int n = n0 + wn * 64 + ni * 16 + lc;
            float vn = v[n];
#pragma unroll
            for (int r = 0; r < 4; ++r) {
                int b = mi * 16 + g * 4 + r;
                float x = acc[mi][ni][r] + decb[(size_t)b * ADIM + n];
                psum[mi][r] = fmaf(fast_tanh(x), vn, psum[mi][r]);
            }
        }
    }
#pragma unroll
    for (int mi = 0; mi < 4; ++mi)
#pragma unroll
        for (int r = 0; r < 4; ++r) {
            float s = psum[mi][r];
            s += __shfl_xor(s, 1);
            s += __shfl_xor(s, 2);
            s += __shfl_xor(s, 4);
            s += __shfl_xor(s, 8);
            psum[mi][r] = s;
        }

    float* red = reinterpret_cast<float*>(As);
    if (lc == 0) {
#pragma unroll
        for (int mi = 0; mi < 4; ++mi)
#pragma unroll
            for (int r = 0; r < 4; ++r) {
                int row = wm * 64 + mi * 16 + g * 4 + r;
                red[row * 2 + wn] = psum[mi][r];
            }
    }
    __syncthreads();
    if (tid < 128)
        atomicAdd(&scores[m0 + tid], red[tid * 2] + red[tid * 2 + 1]);
}

// ---------------------------------------------------------------------------
// Masked softmax over S per batch column, in place. One block per b.
// ---------------------------------------------------------------------------
__global__ __launch_bounds__(256)
void softmax_kernel(const int* __restrict__ lens, float* __restrict__ attn)
{
    const int b   = blockIdx.x;
    const int tid = threadIdx.x;
    const int len = lens[b];

    float sc[4];
#pragma unroll
    for (int k = 0; k < 4; ++k) {
        int s = k * 256 + tid;
        float x = attn[(size_t)s * BSZ + b];
        sc[k] = (s < len) ? x : NEG_MASK;
    }

    __shared__ float red[8];

    float m = fmaxf(fmaxf(sc[0], sc[1]), fmaxf(sc[2], sc[3]));
#pragma unroll
    for (int off = 32; off > 0; off >>= 1) m = fmaxf(m, __shfl_xor(m, off));
    if ((tid & 63) == 0) red[tid >> 6] = m;
    __syncthreads();
    m = fmaxf(fmaxf(red[0], red[1]), fmaxf(red[2], red[3]));

    float e[4];
    float sum = 0.f;
#pragma unroll
    for (int k = 0; k < 4; ++k) { e[k] = expf(sc[k] - m); sum += e[k]; }
#pragma unroll
    for (int off = 32; off > 0; off >>= 1) sum += __shfl_xor(sum, off);
    __syncthreads();
    if ((tid & 63) == 0) red[4 + (tid >> 6)] = sum;
    __syncthreads();
    float total = red[4] + red[5] + red[6] + red[7];
    float inv = 1.f / total;

#pragma unroll
    for (int k = 0; k < 4; ++k) {
        int s = k * 256 + tid;
        attn[(size_t)s * BSZ + b] = e[k] * inv;
    }
}

// ---------------------------------------------------------------------------
// ctx from fp16 hids copy (fast path): halves the read traffic.
// ---------------------------------------------------------------------------
__global__ __launch_bounds__(256)
void ctx16_kernel(const _Float16* __restrict__ hids16, const float* __restrict__ attn,
                  float* __restrict__ ctx)
{
    const int b   = blockIdx.x;
    const int s0  = blockIdx.y * (SRC_LEN / 8);
    const int tid = threadIdx.x;

    float acc[4] = {0.f, 0.f, 0.f, 0.f};
    for (int s = s0; s < s0 + SRC_LEN / 8; ++s) {
        float w = attn[(size_t)s * BSZ + b];
        if (w != 0.f) {
            f16x4 h = *reinterpret_cast<const f16x4*>(
                &hids16[((size_t)s * BSZ + b) * CDIM + tid * 4]);
#pragma unroll
            for (int j = 0; j < 4; ++j) acc[j] = fmaf(w, (float)h[j], acc[j]);
        }
    }
    float* dst = &ctx[(size_t)b * CDIM + tid * 4];
#pragma unroll
    for (int j = 0; j < 4; ++j) atomicAdd(dst + j, acc[j]);
}

__global__ __launch_bounds__(256)
void ctx_kernel(const float* __restrict__ hids, const float* __restrict__ attn,
                float* __restrict__ ctx)
{
    const int b   = blockIdx.x;
    const int s0  = blockIdx.y * (SRC_LEN / 8);
    const int tid = threadIdx.x;

    float4 acc = make_float4(0.f, 0.f, 0.f, 0.f);
    for (int s = s0; s < s0 + SRC_LEN / 8; ++s) {
        float w = attn[(size_t)s * BSZ + b];
        if (w != 0.f) {
            float4 h = *reinterpret_cast<const float4*>(
                &hids[((size_t)s * BSZ + b) * CDIM + tid * 4]);
            acc.x = fmaf(w, h.x, acc.x);
            acc.y = fmaf(w, h.y, acc.y);
            acc.z = fmaf(w, h.z, acc.z);
            acc.w = fmaf(w, h.w, acc.w);
        }
    }
    float* dst = &ctx[(size_t)b * CDIM + tid * 4];
    atomicAdd(dst + 0, acc.x);
    atomicAdd(dst + 1, acc.y);
    atomicAdd(dst + 2, acc.z);
    atomicAdd(dst + 3, acc.w);
}

// ---------------------------------------------------------------------------
extern "C" void kernel_launch(void* const* d_in, const int* in_sizes, int n_in,
                              void* d_out, int out_size, void* d_ws, size_t ws_size,
                              hipStream_t stream)
{
    const float* dsr   = (const float*)d_in[0];
    const float* hids  = (const float*)d_in[1];
    const int*   lens  = (const int*)  d_in[2];
    const float* W_enc = (const float*)d_in[3];
    const float* b_enc = (const float*)d_in[4];
    const float* W_dec = (const float*)d_in[5];
    const float* b_dec = (const float*)d_in[6];
    const float* v     = (const float*)d_in[7];

    float* out  = (float*)d_out;
    float* ctx  = out;                       // [64*1024]
    float* attn = out + BSZ * CDIM;          // [1024*64] scores -> probs

    const size_t decb_b = (size_t)BSZ * ADIM * 4;     // 256 KB
    const size_t wf16_b = (size_t)ADIM * KDIM * 2;    // 2 MB
    const size_t af16_b = (size_t)MROWS * KDIM * 2;   // 128 MB

    float*    decb = (float*)d_ws;
    _Float16* Wf16 = (_Float16*)((char*)d_ws + decb_b);
    _Float16* Af16 = (_Float16*)((char*)d_ws + decb_b + wf16_b);

    const bool fast = ws_size >= decb_b + wf16_b + af16_b;

    hipMemsetAsync(d_out, 0, (size_t)(BSZ * CDIM + SRC_LEN * BSZ) * sizeof(float), stream);

    convert8_kernel<<<ADIM * KDIM / 8 / 256, 256, 0, stream>>>(W_enc, Wf16);
    dec_kernel<<<ADIM / 64, 256, 0, stream>>>(dsr, W_dec, b_dec, b_enc, decb);

    if (fast) {
        convert8_kernel<<<(size_t)MROWS * KDIM / 8 / 256, 256, 0, stream>>>(hids, Af16);
        enc_score_direct<<<4096, 256, 0, stream>>>(Af16, Wf16, decb, v, attn);
        softmax_kernel<<<BSZ, 256, 0, stream>>>(lens, attn);
        ctx16_kernel<<<dim3(BSZ, 8), 256, 0, stream>>>(Af16, attn, ctx);
    } else {
        enc_score_fallback<<<4096, 256, 0, stream>>>(hids, Wf16, decb, v, attn);
        softmax_kernel<<<BSZ, 256, 0, stream>>>(lens, attn);
        ctx_kernel<<<dim3(BSZ, 8), 256, 0, stream>>>(hids, attn, ctx);
    }
}

// Round 5
// 416.951 us; speedup vs baseline: 4.9840x; 1.0377x over previous
//
#include <hip/hip_runtime.h>
#include <math.h>

#define SRC_LEN  1024
#define BSZ      64
#define CDIM     1024
#define ADIM     1024
#define KDIM     1024
#define MROWS    (SRC_LEN * BSZ)
#define NEG_MASK -1000000.0f

// tiled fp16 layout: tile = 128 rows x 64 cols, halfword index within tile:
//   fr = row>>4, lr = row&15, cb = col>>3, ce = col&7
//   hw = fr*1024 + cb*128 + lr*8 + ce          (tile = 8192 hw = 16 KB)
// => fragment read (16 lanes lc x 4 groups g, 16B each) is 1024B contiguous,
//    and global->LDS staging is a plain contiguous copy (both conflict-free).
#define THW 8192

typedef _Float16 f16x8 __attribute__((ext_vector_type(8)));
typedef _Float16 f16x4 __attribute__((ext_vector_type(4)));
typedef float    f32x4 __attribute__((ext_vector_type(4)));

__device__ __forceinline__ float fast_tanh(float x) {
    float e = __expf(2.0f * x);
    return 1.0f - 2.0f / (e + 1.0f);
}

// async global(16B) -> LDS, per-lane global src, wave-uniform LDS base
__device__ __forceinline__ void gload16(const _Float16* g, _Float16* l) {
    __builtin_amdgcn_global_load_lds(
        (const __attribute__((address_space(1))) unsigned int*)g,
        (__attribute__((address_space(3))) unsigned int*)l, 16, 0, 0);
}

// ---------------------------------------------------------------------------
// fp32 [rows][1024] -> fp16 tiled (tiles: (rt * 16 + kt) * THW).
// grid: one block per quarter-tile (2 fr-blocks). 256 threads.
// ---------------------------------------------------------------------------
__global__ __launch_bounds__(256)
void convert_tiled_kernel(const float* __restrict__ in, _Float16* __restrict__ out)
{
    const int bid  = blockIdx.x;
    const int frb  = bid & 3;            // which fr-pair
    const int tile = bid >> 2;
    const int kt   = tile & 15;
    const int rt   = tile >> 4;
    const int t    = threadIdx.x;
    const int fr   = frb * 2 + (t >> 7); // 0..7
    const int u    = t & 127;            // cb*16 + lr
    const int lr   = u & 15;
    const int cb   = u >> 4;

    const size_t row = (size_t)rt * 128 + fr * 16 + lr;
    const int    col = kt * 64 + cb * 8;

    float4 x = *reinterpret_cast<const float4*>(&in[row * KDIM + col]);
    float4 y = *reinterpret_cast<const float4*>(&in[row * KDIM + col + 4]);
    f16x8 o;
    o[0] = (_Float16)x.x; o[1] = (_Float16)x.y;
    o[2] = (_Float16)x.z; o[3] = (_Float16)x.w;
    o[4] = (_Float16)y.x; o[5] = (_Float16)y.y;
    o[6] = (_Float16)y.z; o[7] = (_Float16)y.w;
    *reinterpret_cast<f16x8*>(&out[(size_t)tile * THW + fr * 1024 + u * 8]) = o;
}

// ---------------------------------------------------------------------------
// fp32 -> fp16 linear, 8 elements/thread (fallback path W conversion)
// ---------------------------------------------------------------------------
__global__ __launch_bounds__(256)
void convert8_kernel(const float* __restrict__ in, _Float16* __restrict__ out)
{
    size_t i = ((size_t)blockIdx.x * 256 + threadIdx.x) * 8;
    float4 x = *reinterpret_cast<const float4*>(in + i);
    float4 y = *reinterpret_cast<const float4*>(in + i + 4);
    f16x8 o;
    o[0] = (_Float16)x.x; o[1] = (_Float16)x.y;
    o[2] = (_Float16)x.z; o[3] = (_Float16)x.w;
    o[4] = (_Float16)y.x; o[5] = (_Float16)y.y;
    o[6] = (_Float16)y.z; o[7] = (_Float16)y.w;
    *reinterpret_cast<f16x8*>(out + i) = o;
}

// ---------------------------------------------------------------------------
// decb[b][n] = decoder_state @ W_dec^T + b_dec + b_enc   (fp32)
// ---------------------------------------------------------------------------
__global__ __launch_bounds__(256)
void dec_kernel(const float* __restrict__ A, const float* __restrict__ W,
                const float* __restrict__ b1, const float* __restrict__ b2,
                float* __restrict__ out)
{
    const int n0  = blockIdx.x * 64;
    const int tid = threadIdx.x;
    const int tx  = tid & 15;
    const int ty  = tid >> 4;

    __shared__ float Asl[16][64];
    __shared__ float Bsl[16][64];

    float acc[4][4];
#pragma unroll
    for (int i = 0; i < 4; ++i)
#pragma unroll
        for (int j = 0; j < 4; ++j) acc[i][j] = 0.f;

    const int lr = tid >> 2;
    const int lk = (tid & 3) * 4;

    for (int kb = 0; kb < KDIM; kb += 16) {
        float4 a4 = *reinterpret_cast<const float4*>(&A[(size_t)lr * KDIM + kb + lk]);
        float4 b4 = *reinterpret_cast<const float4*>(&W[(size_t)(n0 + lr) * KDIM + kb + lk]);
        __syncthreads();
        Asl[lk + 0][lr] = a4.x; Asl[lk + 1][lr] = a4.y;
        Asl[lk + 2][lr] = a4.z; Asl[lk + 3][lr] = a4.w;
        Bsl[lk + 0][lr] = b4.x; Bsl[lk + 1][lr] = b4.y;
        Bsl[lk + 2][lr] = b4.z; Bsl[lk + 3][lr] = b4.w;
        __syncthreads();
#pragma unroll
        for (int k = 0; k < 16; ++k) {
            float4 av = *reinterpret_cast<const float4*>(&Asl[k][ty * 4]);
            float4 bv = *reinterpret_cast<const float4*>(&Bsl[k][tx * 4]);
            float am[4] = {av.x, av.y, av.z, av.w};
            float bn[4] = {bv.x, bv.y, bv.z, bv.w};
#pragma unroll
            for (int i = 0; i < 4; ++i)
#pragma unroll
                for (int j = 0; j < 4; ++j)
                    acc[i][j] = fmaf(am[i], bn[j], acc[i][j]);
        }
    }
#pragma unroll
    for (int i = 0; i < 4; ++i) {
        int m = ty * 4 + i;
#pragma unroll
        for (int j = 0; j < 4; ++j) {
            int n = n0 + tx * 4 + j;
            out[(size_t)m * ADIM + n] = acc[i][j] + b1[n] + b2[n];
        }
    }
}

// ---------------------------------------------------------------------------
// FAST PATH: fused enc-projection + tanh + v-dot.
// 128x128 tile, BK=64, 4 waves (2x2), global_load_lds(16B), pre-tiled
// fragment-major LDS image (conflict-free staging AND fragment reads).
// XCD-grouped bid decode (A-panel L2 reuse).
// ---------------------------------------------------------------------------
__global__ __launch_bounds__(256)
void enc_score_direct(const _Float16* __restrict__ At,   // tiled [512*16]*THW
                      const _Float16* __restrict__ Bt,   // tiled [8*16]*THW
                      const float* __restrict__ decb,    // [64][1024]
                      const float* __restrict__ v,       // [1024]
                      float* __restrict__ scores)        // [65536]
{
    const int bid = blockIdx.x;
    const int nb  = (bid >> 3) & 7;
    const int mb  = (bid & 7) + ((bid >> 6) << 3);
    const int m0 = mb * 128, n0 = nb * 128;
    const int tid  = threadIdx.x;
    const int lane = tid & 63;
    const int wid  = tid >> 6;
    const int wm   = wid >> 1, wn = wid & 1;
    const int lc   = lane & 15, g = lane >> 4;

    __shared__ __align__(16) _Float16 As[THW];
    __shared__ __align__(16) _Float16 Bs[THW];

    f32x4 acc[4][4];
#pragma unroll
    for (int i = 0; i < 4; ++i)
#pragma unroll
        for (int j = 0; j < 4; ++j) acc[i][j] = (f32x4){0.f, 0.f, 0.f, 0.f};

    for (int kt = 0; kt < 16; ++kt) {
        const _Float16* Ag = At + (size_t)(mb * 16 + kt) * THW;
        const _Float16* Bg = Bt + (size_t)(nb * 16 + kt) * THW;
        __syncthreads();   // all waves done reading previous tile
#pragma unroll
        for (int i = 0; i < 4; ++i) {
            int c = wid * 4 + i;                 // chunk 0..15, 1KB each
            gload16(Ag + c * 512 + lane * 8, &As[c * 512]);
            gload16(Bg + c * 512 + lane * 8, &Bs[c * 512]);
        }
        asm volatile("s_waitcnt vmcnt(0)" ::: "memory");
        __syncthreads();   // staged tile visible to all waves
#pragma unroll
        for (int ks = 0; ks < 2; ++ks) {
            f16x8 af[4], bf[4];
#pragma unroll
            for (int mi = 0; mi < 4; ++mi)
                af[mi] = *reinterpret_cast<const f16x8*>(
                    &As[(wm * 4 + mi) * 1024 + ks * 512 + g * 128 + lc * 8]);
#pragma unroll
            for (int ni = 0; ni < 4; ++ni)
                bf[ni] = *reinterpret_cast<const f16x8*>(
                    &Bs[(wn * 4 + ni) * 1024 + ks * 512 + g * 128 + lc * 8]);
#pragma unroll
            for (int mi = 0; mi < 4; ++mi)
#pragma unroll
                for (int ni = 0; ni < 4; ++ni)
                    acc[mi][ni] = __builtin_amdgcn_mfma_f32_16x16x32_f16(
                        af[mi], bf[ni], acc[mi][ni], 0, 0, 0);
        }
    }

    // ---- fused epilogue: tanh + v-dot + row reduce ----
    __syncthreads();

    float psum[4][4];
#pragma unroll
    for (int mi = 0; mi < 4; ++mi)
#pragma unroll
        for (int r = 0; r < 4; ++r) psum[mi][r] = 0.f;

#pragma unroll
    for (int mi = 0; mi < 4; ++mi) {
#pragma unroll
        for (int ni = 0; ni < 4; ++ni) {
            int n = n0 + wn * 64 + ni * 16 + lc;
            float vn = v[n];
#pragma unroll
            for (int r = 0; r < 4; ++r) {
                int b = mi * 16 + g * 4 + r;          // m & 63
                float x = acc[mi][ni][r] + decb[(size_t)b * ADIM + n];
                psum[mi][r] = fmaf(fast_tanh(x), vn, psum[mi][r]);
            }
        }
    }
#pragma unroll
    for (int mi = 0; mi < 4; ++mi)
#pragma unroll
        for (int r = 0; r < 4; ++r) {
            float s = psum[mi][r];
            s += __shfl_xor(s, 1);
            s += __shfl_xor(s, 2);
            s += __shfl_xor(s, 4);
            s += __shfl_xor(s, 8);
            psum[mi][r] = s;
        }

    float* red = reinterpret_cast<float*>(As);   // [128][2]
    if (lc == 0) {
#pragma unroll
        for (int mi = 0; mi < 4; ++mi)
#pragma unroll
            for (int r = 0; r < 4; ++r) {
                int row = wm * 64 + mi * 16 + g * 4 + r;
                red[row * 2 + wn] = psum[mi][r];
            }
    }
    __syncthreads();
    if (tid < 128)
        atomicAdd(&scores[m0 + tid], red[tid * 2] + red[tid * 2 + 1]);
}

// ---------------------------------------------------------------------------
// FALLBACK (ws too small): reg-staged fp32-A version (R3).
// ---------------------------------------------------------------------------
__global__ __launch_bounds__(256)
void enc_score_fallback(const float* __restrict__ A,
                        const _Float16* __restrict__ Bw,
                        const float* __restrict__ decb,
                        const float* __restrict__ v,
                        float* __restrict__ scores)
{
    const int bid = blockIdx.x;
    const int nb  = (bid >> 3) & 7;
    const int mb  = (bid & 7) + ((bid >> 6) << 3);
    const int m0 = mb * 128, n0 = nb * 128;
    const int tid  = threadIdx.x;
    const int lane = tid & 63;
    const int wid  = tid >> 6;
    const int wm   = wid >> 1, wn = wid & 1;
    const int lc   = lane & 15, g = lane >> 4;

    __shared__ __align__(16) _Float16 As[128 * 64];
    __shared__ __align__(16) _Float16 Bs[128 * 64];

    const int srow = tid >> 1;
    const int scol = (tid & 1) * 32;
    const int sw   = (srow & 7) << 3;

    f32x4 acc[4][4];
#pragma unroll
    for (int i = 0; i < 4; ++i)
#pragma unroll
        for (int j = 0; j < 4; ++j) acc[i][j] = (f32x4){0.f, 0.f, 0.f, 0.f};

    const float*    Aptr = A  + (size_t)(m0 + srow) * KDIM + scol;
    const _Float16* Bptr = Bw + (size_t)(n0 + srow) * KDIM + scol;

    float4 aR[8];
    uint4  bR[4];
#pragma unroll
    for (int i = 0; i < 8; ++i) aR[i] = reinterpret_cast<const float4*>(Aptr)[i];
#pragma unroll
    for (int i = 0; i < 4; ++i) bR[i] = reinterpret_cast<const uint4*>(Bptr)[i];

    for (int kb = 0; kb < KDIM; kb += 64) {
        __syncthreads();
#pragma unroll
        for (int w = 0; w < 4; ++w) {
            float4 x = aR[2 * w], y = aR[2 * w + 1];
            f16x8 p;
            p[0] = (_Float16)x.x; p[1] = (_Float16)x.y;
            p[2] = (_Float16)x.z; p[3] = (_Float16)x.w;
            p[4] = (_Float16)y.x; p[5] = (_Float16)y.y;
            p[6] = (_Float16)y.z; p[7] = (_Float16)y.w;
            int hw = (srow * 64 + scol + 8 * w) ^ sw;
            *reinterpret_cast<f16x8*>(&As[hw]) = p;
            *reinterpret_cast<uint4*>(&Bs[hw]) = bR[w];
        }
        __syncthreads();
        if (kb + 64 < KDIM) {
#pragma unroll
            for (int i = 0; i < 8; ++i)
                aR[i] = reinterpret_cast<const float4*>(Aptr + kb + 64)[i];
#pragma unroll
            for (int i = 0; i < 4; ++i)
                bR[i] = reinterpret_cast<const uint4*>(Bptr + kb + 64)[i];
        }
#pragma unroll
        for (int ks = 0; ks < 2; ++ks) {
            f16x8 af[4], bf[4];
#pragma unroll
            for (int mi = 0; mi < 4; ++mi) {
                int r  = wm * 64 + mi * 16 + lc;
                int hw = (r * 64 + ks * 32 + g * 8) ^ ((r & 7) << 3);
                af[mi] = *reinterpret_cast<const f16x8*>(&As[hw]);
            }
#pragma unroll
            for (int ni = 0; ni < 4; ++ni) {
                int r  = wn * 64 + ni * 16 + lc;
                int hw = (r * 64 + ks * 32 + g * 8) ^ ((r & 7) << 3);
                bf[ni] = *reinterpret_cast<const f16x8*>(&Bs[hw]);
            }
#pragma unroll
            for (int mi = 0; mi < 4; ++mi)
#pragma unroll
                for (int ni = 0; ni < 4; ++ni)
                    acc[mi][ni] = __builtin_amdgcn_mfma_f32_16x16x32_f16(
                        af[mi], bf[ni], acc[mi][ni], 0, 0, 0);
        }
    }

    __syncthreads();

    float psum[4][4];
#pragma unroll
    for (int mi = 0; mi < 4; ++mi)
#pragma unroll
        for (int r = 0; r < 4; ++r) psum[mi][r] = 0.f;

#pragma unroll
    for (int mi = 0; mi < 4; ++mi) {
#pragma unroll
        for (int ni = 0; ni < 4; ++ni) {
            int n = n0 + wn * 64 + ni * 16 + lc;
            float vn = v[n];
#pragma unroll
            for (int r = 0; r < 4; ++r) {
                int b = mi * 16 + g * 4 + r;
                float x = acc[mi][ni][r] + decb[(size_t)b * ADIM + n];
                psum[mi][r] = fmaf(fast_tanh(x), vn, psum[mi][r]);
            }
        }
    }
#pragma unroll
    for (int mi = 0; mi < 4; ++mi)
#pragma unroll
        for (int r = 0; r < 4; ++r) {
            float s = psum[mi][r];
            s += __shfl_xor(s, 1);
            s += __shfl_xor(s, 2);
            s += __shfl_xor(s, 4);
            s += __shfl_xor(s, 8);
            psum[mi][r] = s;
        }

    float* red = reinterpret_cast<float*>(As);
    if (lc == 0) {
#pragma unroll
        for (int mi = 0; mi < 4; ++mi)
#pragma unroll
            for (int r = 0; r < 4; ++r) {
                int row = wm * 64 + mi * 16 + g * 4 + r;
                red[row * 2 + wn] = psum[mi][r];
            }
    }
    __syncthreads();
    if (tid < 128)
        atomicAdd(&scores[m0 + tid], red[tid * 2] + red[tid * 2 + 1]);
}

// ---------------------------------------------------------------------------
// Masked softmax over S per batch column, in place. One block per b.
// ---------------------------------------------------------------------------
__global__ __launch_bounds__(256)
void softmax_kernel(const int* __restrict__ lens, float* __restrict__ attn)
{
    const int b   = blockIdx.x;
    const int tid = threadIdx.x;
    const int len = lens[b];

    float sc[4];
#pragma unroll
    for (int k = 0; k < 4; ++k) {
        int s = k * 256 + tid;
        float x = attn[(size_t)s * BSZ + b];
        sc[k] = (s < len) ? x : NEG_MASK;
    }

    __shared__ float red[8];

    float m = fmaxf(fmaxf(sc[0], sc[1]), fmaxf(sc[2], sc[3]));
#pragma unroll
    for (int off = 32; off > 0; off >>= 1) m = fmaxf(m, __shfl_xor(m, off));
    if ((tid & 63) == 0) red[tid >> 6] = m;
    __syncthreads();
    m = fmaxf(fmaxf(red[0], red[1]), fmaxf(red[2], red[3]));

    float e[4];
    float sum = 0.f;
#pragma unroll
    for (int k = 0; k < 4; ++k) { e[k] = expf(sc[k] - m); sum += e[k]; }
#pragma unroll
    for (int off = 32; off > 0; off >>= 1) sum += __shfl_xor(sum, off);
    __syncthreads();
    if ((tid & 63) == 0) red[4 + (tid >> 6)] = sum;
    __syncthreads();
    float total = red[4] + red[5] + red[6] + red[7];
    float inv = 1.f / total;

#pragma unroll
    for (int k = 0; k < 4; ++k) {
        int s = k * 256 + tid;
        attn[(size_t)s * BSZ + b] = e[k] * inv;
    }
}

// ---------------------------------------------------------------------------
// ctx[b][c] = sum_s attn[s][b] * hids[s][b][c]   (fp32 source, coalesced)
// ---------------------------------------------------------------------------
__global__ __launch_bounds__(256)
void ctx_kernel(const float* __restrict__ hids, const float* __restrict__ attn,
                float* __restrict__ ctx)
{
    const int b   = blockIdx.x;
    const int s0  = blockIdx.y * (SRC_LEN / 8);
    const int tid = threadIdx.x;

    float4 acc = make_float4(0.f, 0.f, 0.f, 0.f);
    for (int s = s0; s < s0 + SRC_LEN / 8; ++s) {
        float w = attn[(size_t)s * BSZ + b];
        if (w != 0.f) {
            float4 h = *reinterpret_cast<const float4*>(
                &hids[((size_t)s * BSZ + b) * CDIM + tid * 4]);
            acc.x = fmaf(w, h.x, acc.x);
            acc.y = fmaf(w, h.y, acc.y);
            acc.z = fmaf(w, h.z, acc.z);
            acc.w = fmaf(w, h.w, acc.w);
        }
    }
    float* dst = &ctx[(size_t)b * CDIM + tid * 4];
    atomicAdd(dst + 0, acc.x);
    atomicAdd(dst + 1, acc.y);
    atomicAdd(dst + 2, acc.z);
    atomicAdd(dst + 3, acc.w);
}

// ---------------------------------------------------------------------------
extern "C" void kernel_launch(void* const* d_in, const int* in_sizes, int n_in,
                              void* d_out, int out_size, void* d_ws, size_t ws_size,
                              hipStream_t stream)
{
    const float* dsr   = (const float*)d_in[0];
    const float* hids  = (const float*)d_in[1];
    const int*   lens  = (const int*)  d_in[2];
    const float* W_enc = (const float*)d_in[3];
    const float* b_enc = (const float*)d_in[4];
    const float* W_dec = (const float*)d_in[5];
    const float* b_dec = (const float*)d_in[6];
    const float* v     = (const float*)d_in[7];

    float* out  = (float*)d_out;
    float* ctx  = out;                       // [64*1024]
    float* attn = out + BSZ * CDIM;          // [1024*64] scores -> probs

    const size_t decb_b = (size_t)BSZ * ADIM * 4;     // 256 KB
    const size_t wf16_b = (size_t)ADIM * KDIM * 2;    // 2 MB
    const size_t af16_b = (size_t)MROWS * KDIM * 2;   // 128 MB

    float*    decb = (float*)d_ws;
    _Float16* Wt   = (_Float16*)((char*)d_ws + decb_b);
    _Float16* At   = (_Float16*)((char*)d_ws + decb_b + wf16_b);

    const bool fast = ws_size >= decb_b + wf16_b + af16_b;

    hipMemsetAsync(d_out, 0, (size_t)(BSZ * CDIM + SRC_LEN * BSZ) * sizeof(float), stream);

    dec_kernel<<<ADIM / 64, 256, 0, stream>>>(dsr, W_dec, b_dec, b_enc, decb);

    if (fast) {
        convert_tiled_kernel<<<(ADIM / 128) * 16 * 4, 256, 0, stream>>>(W_enc, Wt);
        convert_tiled_kernel<<<(MROWS / 128) * 16 * 4, 256, 0, stream>>>(hids, At);
        enc_score_direct<<<4096, 256, 0, stream>>>(At, Wt, decb, v, attn);
    } else {
        convert8_kernel<<<ADIM * KDIM / 8 / 256, 256, 0, stream>>>(W_enc, Wt);
        enc_score_fallback<<<4096, 256, 0, stream>>>(hids, Wt, decb, v, attn);
    }
    softmax_kernel<<<BSZ, 256, 0, stream>>>(lens, attn);
    ctx_kernel<<<dim3(BSZ, 8), 256, 0, stream>>>(hids, attn, ctx);
}

// Round 6
// 376.341 us; speedup vs baseline: 5.5218x; 1.1079x over previous
//
#include <hip/hip_runtime.h>
#include <math.h>

#define SRC_LEN  1024
#define BSZ      64
#define CDIM     1024
#define ADIM     1024
#define KDIM     1024
#define MROWS    (SRC_LEN * BSZ)
#define NEG_MASK -1000000.0f

// tiled fp16 layout: tile = 128 rows x 64 cols, halfword index within tile:
//   fr = row>>4, lr = row&15, cb = col>>3, ce = col&7
//   hw = fr*1024 + cb*128 + lr*8 + ce          (tile = 8192 hw = 16 KB)
// => fragment ds_read_b128 is conflict-free (64 lanes cover 1KB contiguous)
//    and global->LDS staging is a plain contiguous copy.
#define THW 8192

typedef _Float16 f16x8 __attribute__((ext_vector_type(8)));
typedef _Float16 f16x4 __attribute__((ext_vector_type(4)));
typedef float    f32x4 __attribute__((ext_vector_type(4)));

__device__ __forceinline__ float fast_tanh(float x) {
    float e = __expf(2.0f * x);
    return 1.0f - 2.0f / (e + 1.0f);
}

// async global(16B) -> LDS, per-lane global src, wave-uniform LDS base
__device__ __forceinline__ void gload16(const _Float16* g, _Float16* l) {
    __builtin_amdgcn_global_load_lds(
        (const __attribute__((address_space(1))) unsigned int*)g,
        (__attribute__((address_space(3))) unsigned int*)l, 16, 0, 0);
}

// ---------------------------------------------------------------------------
// fp32 [rows][1024] -> fp16 tiled (tiles: (rt * 16 + kt) * THW).
// ---------------------------------------------------------------------------
__global__ __launch_bounds__(256)
void convert_tiled_kernel(const float* __restrict__ in, _Float16* __restrict__ out)
{
    const int bid  = blockIdx.x;
    const int frb  = bid & 3;
    const int tile = bid >> 2;
    const int kt   = tile & 15;
    const int rt   = tile >> 4;
    const int t    = threadIdx.x;
    const int fr   = frb * 2 + (t >> 7);
    const int u    = t & 127;            // cb*16 + lr
    const int lr   = u & 15;
    const int cb   = u >> 4;

    const size_t row = (size_t)rt * 128 + fr * 16 + lr;
    const int    col = kt * 64 + cb * 8;

    float4 x = *reinterpret_cast<const float4*>(&in[row * KDIM + col]);
    float4 y = *reinterpret_cast<const float4*>(&in[row * KDIM + col + 4]);
    f16x8 o;
    o[0] = (_Float16)x.x; o[1] = (_Float16)x.y;
    o[2] = (_Float16)x.z; o[3] = (_Float16)x.w;
    o[4] = (_Float16)y.x; o[5] = (_Float16)y.y;
    o[6] = (_Float16)y.z; o[7] = (_Float16)y.w;
    *reinterpret_cast<f16x8*>(&out[(size_t)tile * THW + fr * 1024 + u * 8]) = o;
}

// ---------------------------------------------------------------------------
// fp32 -> fp16 linear (fallback path W conversion)
// ---------------------------------------------------------------------------
__global__ __launch_bounds__(256)
void convert8_kernel(const float* __restrict__ in, _Float16* __restrict__ out)
{
    size_t i = ((size_t)blockIdx.x * 256 + threadIdx.x) * 8;
    float4 x = *reinterpret_cast<const float4*>(in + i);
    float4 y = *reinterpret_cast<const float4*>(in + i + 4);
    f16x8 o;
    o[0] = (_Float16)x.x; o[1] = (_Float16)x.y;
    o[2] = (_Float16)x.z; o[3] = (_Float16)x.w;
    o[4] = (_Float16)y.x; o[5] = (_Float16)y.y;
    o[6] = (_Float16)y.z; o[7] = (_Float16)y.w;
    *reinterpret_cast<f16x8*>(out + i) = o;
}

// ---------------------------------------------------------------------------
// decb[b][n] += decoder_state @ W_dec^T  (k-split, atomic; NO bias here)
// grid (16 n-tiles, 4 k-chunks). decb must be zeroed first.
// ---------------------------------------------------------------------------
__global__ __launch_bounds__(256)
void dec_kernel(const float* __restrict__ A, const float* __restrict__ W,
                float* __restrict__ out)
{
    const int n0  = blockIdx.x * 64;
    const int k0  = blockIdx.y * 256;
    const int tid = threadIdx.x;
    const int tx  = tid & 15;
    const int ty  = tid >> 4;

    __shared__ float Asl[16][64];
    __shared__ float Bsl[16][64];

    float acc[4][4];
#pragma unroll
    for (int i = 0; i < 4; ++i)
#pragma unroll
        for (int j = 0; j < 4; ++j) acc[i][j] = 0.f;

    const int lr = tid >> 2;
    const int lk = (tid & 3) * 4;

    for (int kb = k0; kb < k0 + 256; kb += 16) {
        float4 a4 = *reinterpret_cast<const float4*>(&A[(size_t)lr * KDIM + kb + lk]);
        float4 b4 = *reinterpret_cast<const float4*>(&W[(size_t)(n0 + lr) * KDIM + kb + lk]);
        __syncthreads();
        Asl[lk + 0][lr] = a4.x; Asl[lk + 1][lr] = a4.y;
        Asl[lk + 2][lr] = a4.z; Asl[lk + 3][lr] = a4.w;
        Bsl[lk + 0][lr] = b4.x; Bsl[lk + 1][lr] = b4.y;
        Bsl[lk + 2][lr] = b4.z; Bsl[lk + 3][lr] = b4.w;
        __syncthreads();
#pragma unroll
        for (int k = 0; k < 16; ++k) {
            float4 av = *reinterpret_cast<const float4*>(&Asl[k][ty * 4]);
            float4 bv = *reinterpret_cast<const float4*>(&Bsl[k][tx * 4]);
            float am[4] = {av.x, av.y, av.z, av.w};
            float bn[4] = {bv.x, bv.y, bv.z, bv.w};
#pragma unroll
            for (int i = 0; i < 4; ++i)
#pragma unroll
                for (int j = 0; j < 4; ++j)
                    acc[i][j] = fmaf(am[i], bn[j], acc[i][j]);
        }
    }
#pragma unroll
    for (int i = 0; i < 4; ++i) {
        int m = ty * 4 + i;
#pragma unroll
        for (int j = 0; j < 4; ++j) {
            int n = n0 + tx * 4 + j;
            atomicAdd(&out[(size_t)m * ADIM + n], acc[i][j]);
        }
    }
}

// ---------------------------------------------------------------------------
// FAST PATH: fused enc-projection + tanh + v-dot.
// 128x128 tile, BK=64, 4 waves, pre-tiled fragment-major layout,
// DOUBLE-BUFFERED 2-phase pipeline: stage(t+1) || compute(t), counted
// vmcnt(8) (never 0 in loop), raw s_barrier. XCD-grouped bid decode.
// ---------------------------------------------------------------------------
__global__ __launch_bounds__(256, 2)
void enc_score_direct(const _Float16* __restrict__ At,   // tiled [512*16]*THW
                      const _Float16* __restrict__ Bt,   // tiled [8*16]*THW
                      const float* __restrict__ decb,    // [64][1024] (no bias)
                      const float* __restrict__ be,      // b_enc [1024]
                      const float* __restrict__ bd,      // b_dec [1024]
                      const float* __restrict__ v,       // [1024]
                      float* __restrict__ scores)        // [65536]
{
    const int bid = blockIdx.x;
    const int nb  = (bid >> 3) & 7;
    const int mb  = (bid & 7) + ((bid >> 6) << 3);
    const int m0 = mb * 128, n0 = nb * 128;
    const int tid  = threadIdx.x;
    const int lane = tid & 63;
    const int wid  = tid >> 6;
    const int wm   = wid >> 1, wn = wid & 1;
    const int lc   = lane & 15, g = lane >> 4;

    __shared__ __align__(16) _Float16 As[2][THW];   // 32 KB
    __shared__ __align__(16) _Float16 Bs[2][THW];   // 32 KB

    f32x4 acc[4][4];
#pragma unroll
    for (int i = 0; i < 4; ++i)
#pragma unroll
        for (int j = 0; j < 4; ++j) acc[i][j] = (f32x4){0.f, 0.f, 0.f, 0.f};

    const _Float16* Abase = At + (size_t)(mb * 16) * THW;
    const _Float16* Bbase = Bt + (size_t)(nb * 16) * THW;

    // ---- prologue: stage tile 0 into buffer 0 ----
#pragma unroll
    for (int i = 0; i < 4; ++i) {
        int c = wid * 4 + i;                 // chunk 0..15, 1KB each
        gload16(Abase + c * 512 + lane * 8, &As[0][c * 512]);
        gload16(Bbase + c * 512 + lane * 8, &Bs[0][c * 512]);
    }

    for (int kt = 0; kt < 16; ++kt) {
        const int cur = kt & 1;
        if (kt < 15) {
            // issue next tile's loads into the other buffer (8 per wave)
            const _Float16* Ag = Abase + (size_t)(kt + 1) * THW;
            const _Float16* Bg = Bbase + (size_t)(kt + 1) * THW;
#pragma unroll
            for (int i = 0; i < 4; ++i) {
                int c = wid * 4 + i;
                gload16(Ag + c * 512 + lane * 8, &As[cur ^ 1][c * 512]);
                gload16(Bg + c * 512 + lane * 8, &Bs[cur ^ 1][c * 512]);
            }
            // drain only tile kt's 8 loads (issued one iteration ago)
            asm volatile("s_waitcnt vmcnt(8)" ::: "memory");
        } else {
            asm volatile("s_waitcnt vmcnt(0)" ::: "memory");
        }
        __builtin_amdgcn_s_barrier();        // tile kt staged for all waves
        asm volatile("" ::: "memory");

        f16x8 af[2][4], bf[2][4];
#pragma unroll
        for (int ks = 0; ks < 2; ++ks) {
#pragma unroll
            for (int mi = 0; mi < 4; ++mi)
                af[ks][mi] = *reinterpret_cast<const f16x8*>(
                    &As[cur][(wm * 4 + mi) * 1024 + ks * 512 + g * 128 + lc * 8]);
#pragma unroll
            for (int ni = 0; ni < 4; ++ni)
                bf[ks][ni] = *reinterpret_cast<const f16x8*>(
                    &Bs[cur][(wn * 4 + ni) * 1024 + ks * 512 + g * 128 + lc * 8]);
        }
#pragma unroll
        for (int ks = 0; ks < 2; ++ks)
#pragma unroll
            for (int mi = 0; mi < 4; ++mi)
#pragma unroll
                for (int ni = 0; ni < 4; ++ni)
                    acc[mi][ni] = __builtin_amdgcn_mfma_f32_16x16x32_f16(
                        af[ks][mi], bf[ks][ni], acc[mi][ni], 0, 0, 0);

        // all this wave's LDS reads done, then block-wide barrier so the
        // next iteration may overwrite buf[cur^? -> buf written at kt+1 is cur]
        asm volatile("s_waitcnt lgkmcnt(0)" ::: "memory");
        __builtin_amdgcn_sched_barrier(0);
        __builtin_amdgcn_s_barrier();
        asm volatile("" ::: "memory");
    }

    // ---- fused epilogue: tanh + v-dot + row reduce ----
    __syncthreads();

    float psum[4][4];
#pragma unroll
    for (int mi = 0; mi < 4; ++mi)
#pragma unroll
        for (int r = 0; r < 4; ++r) psum[mi][r] = 0.f;

#pragma unroll
    for (int mi = 0; mi < 4; ++mi) {
#pragma unroll
        for (int ni = 0; ni < 4; ++ni) {
            int n = n0 + wn * 64 + ni * 16 + lc;
            float vn = v[n];
            float bb = be[n] + bd[n];
#pragma unroll
            for (int r = 0; r < 4; ++r) {
                int b = mi * 16 + g * 4 + r;          // m & 63
                float x = acc[mi][ni][r] + decb[(size_t)b * ADIM + n] + bb;
                psum[mi][r] = fmaf(fast_tanh(x), vn, psum[mi][r]);
            }
        }
    }
#pragma unroll
    for (int mi = 0; mi < 4; ++mi)
#pragma unroll
        for (int r = 0; r < 4; ++r) {
            float s = psum[mi][r];
            s += __shfl_xor(s, 1);
            s += __shfl_xor(s, 2);
            s += __shfl_xor(s, 4);
            s += __shfl_xor(s, 8);
            psum[mi][r] = s;
        }

    float* red = reinterpret_cast<float*>(&As[0][0]);   // [128][2]
    if (lc == 0) {
#pragma unroll
        for (int mi = 0; mi < 4; ++mi)
#pragma unroll
            for (int r = 0; r < 4; ++r) {
                int row = wm * 64 + mi * 16 + g * 4 + r;
                red[row * 2 + wn] = psum[mi][r];
            }
    }
    __syncthreads();
    if (tid < 128)
        atomicAdd(&scores[m0 + tid], red[tid * 2] + red[tid * 2 + 1]);
}

// ---------------------------------------------------------------------------
// FALLBACK (ws too small): reg-staged fp32-A version.
// ---------------------------------------------------------------------------
__global__ __launch_bounds__(256)
void enc_score_fallback(const float* __restrict__ A,
                        const _Float16* __restrict__ Bw,
                        const float* __restrict__ decb,
                        const float* __restrict__ be,
                        const float* __restrict__ bd,
                        const float* __restrict__ v,
                        float* __restrict__ scores)
{
    const int bid = blockIdx.x;
    const int nb  = (bid >> 3) & 7;
    const int mb  = (bid & 7) + ((bid >> 6) << 3);
    const int m0 = mb * 128, n0 = nb * 128;
    const int tid  = threadIdx.x;
    const int lane = tid & 63;
    const int wid  = tid >> 6;
    const int wm   = wid >> 1, wn = wid & 1;
    const int lc   = lane & 15, g = lane >> 4;

    __shared__ __align__(16) _Float16 As[128 * 64];
    __shared__ __align__(16) _Float16 Bs[128 * 64];

    const int srow = tid >> 1;
    const int scol = (tid & 1) * 32;
    const int sw   = (srow & 7) << 3;

    f32x4 acc[4][4];
#pragma unroll
    for (int i = 0; i < 4; ++i)
#pragma unroll
        for (int j = 0; j < 4; ++j) acc[i][j] = (f32x4){0.f, 0.f, 0.f, 0.f};

    const float*    Aptr = A  + (size_t)(m0 + srow) * KDIM + scol;
    const _Float16* Bptr = Bw + (size_t)(n0 + srow) * KDIM + scol;

    float4 aR[8];
    uint4  bR[4];
#pragma unroll
    for (int i = 0; i < 8; ++i) aR[i] = reinterpret_cast<const float4*>(Aptr)[i];
#pragma unroll
    for (int i = 0; i < 4; ++i) bR[i] = reinterpret_cast<const uint4*>(Bptr)[i];

    for (int kb = 0; kb < KDIM; kb += 64) {
        __syncthreads();
#pragma unroll
        for (int w = 0; w < 4; ++w) {
            float4 x = aR[2 * w], y = aR[2 * w + 1];
            f16x8 p;
            p[0] = (_Float16)x.x; p[1] = (_Float16)x.y;
            p[2] = (_Float16)x.z; p[3] = (_Float16)x.w;
            p[4] = (_Float16)y.x; p[5] = (_Float16)y.y;
            p[6] = (_Float16)y.z; p[7] = (_Float16)y.w;
            int hw = (srow * 64 + scol + 8 * w) ^ sw;
            *reinterpret_cast<f16x8*>(&As[hw]) = p;
            *reinterpret_cast<uint4*>(&Bs[hw]) = bR[w];
        }
        __syncthreads();
        if (kb + 64 < KDIM) {
#pragma unroll
            for (int i = 0; i < 8; ++i)
                aR[i] = reinterpret_cast<const float4*>(Aptr + kb + 64)[i];
#pragma unroll
            for (int i = 0; i < 4; ++i)
                bR[i] = reinterpret_cast<const uint4*>(Bptr + kb + 64)[i];
        }
#pragma unroll
        for (int ks = 0; ks < 2; ++ks) {
            f16x8 af[4], bf[4];
#pragma unroll
            for (int mi = 0; mi < 4; ++mi) {
                int r  = wm * 64 + mi * 16 + lc;
                int hw = (r * 64 + ks * 32 + g * 8) ^ ((r & 7) << 3);
                af[mi] = *reinterpret_cast<const f16x8*>(&As[hw]);
            }
#pragma unroll
            for (int ni = 0; ni < 4; ++ni) {
                int r  = wn * 64 + ni * 16 + lc;
                int hw = (r * 64 + ks * 32 + g * 8) ^ ((r & 7) << 3);
                bf[ni] = *reinterpret_cast<const f16x8*>(&Bs[hw]);
            }
#pragma unroll
            for (int mi = 0; mi < 4; ++mi)
#pragma unroll
                for (int ni = 0; ni < 4; ++ni)
                    acc[mi][ni] = __builtin_amdgcn_mfma_f32_16x16x32_f16(
                        af[mi], bf[ni], acc[mi][ni], 0, 0, 0);
        }
    }

    __syncthreads();

    float psum[4][4];
#pragma unroll
    for (int mi = 0; mi < 4; ++mi)
#pragma unroll
        for (int r = 0; r < 4; ++r) psum[mi][r] = 0.f;

#pragma unroll
    for (int mi = 0; mi < 4; ++mi) {
#pragma unroll
        for (int ni = 0; ni < 4; ++ni) {
            int n = n0 + wn * 64 + ni * 16 + lc;
            float vn = v[n];
            float bb = be[n] + bd[n];
#pragma unroll
            for (int r = 0; r < 4; ++r) {
                int b = mi * 16 + g * 4 + r;
                float x = acc[mi][ni][r] + decb[(size_t)b * ADIM + n] + bb;
                psum[mi][r] = fmaf(fast_tanh(x), vn, psum[mi][r]);
            }
        }
    }
#pragma unroll
    for (int mi = 0; mi < 4; ++mi)
#pragma unroll
        for (int r = 0; r < 4; ++r) {
            float s = psum[mi][r];
            s += __shfl_xor(s, 1);
            s += __shfl_xor(s, 2);
            s += __shfl_xor(s, 4);
            s += __shfl_xor(s, 8);
            psum[mi][r] = s;
        }

    float* red = reinterpret_cast<float*>(As);
    if (lc == 0) {
#pragma unroll
        for (int mi = 0; mi < 4; ++mi)
#pragma unroll
            for (int r = 0; r < 4; ++r) {
                int row = wm * 64 + mi * 16 + g * 4 + r;
                red[row * 2 + wn] = psum[mi][r];
            }
    }
    __syncthreads();
    if (tid < 128)
        atomicAdd(&scores[m0 + tid], red[tid * 2] + red[tid * 2 + 1]);
}

// ---------------------------------------------------------------------------
// Masked softmax over S per batch column, in place. One block per b.
// ---------------------------------------------------------------------------
__global__ __launch_bounds__(256)
void softmax_kernel(const int* __restrict__ lens, float* __restrict__ attn)
{
    const int b   = blockIdx.x;
    const int tid = threadIdx.x;
    const int len = lens[b];

    float sc[4];
#pragma unroll
    for (int k = 0; k < 4; ++k) {
        int s = k * 256 + tid;
        float x = attn[(size_t)s * BSZ + b];
        sc[k] = (s < len) ? x : NEG_MASK;
    }

    __shared__ float red[8];

    float m = fmaxf(fmaxf(sc[0], sc[1]), fmaxf(sc[2], sc[3]));
#pragma unroll
    for (int off = 32; off > 0; off >>= 1) m = fmaxf(m, __shfl_xor(m, off));
    if ((tid & 63) == 0) red[tid >> 6] = m;
    __syncthreads();
    m = fmaxf(fmaxf(red[0], red[1]), fmaxf(red[2], red[3]));

    float e[4];
    float sum = 0.f;
#pragma unroll
    for (int k = 0; k < 4; ++k) { e[k] = expf(sc[k] - m); sum += e[k]; }
#pragma unroll
    for (int off = 32; off > 0; off >>= 1) sum += __shfl_xor(sum, off);
    __syncthreads();
    if ((tid & 63) == 0) red[4 + (tid >> 6)] = sum;
    __syncthreads();
    float total = red[4] + red[5] + red[6] + red[7];
    float inv = 1.f / total;

#pragma unroll
    for (int k = 0; k < 4; ++k) {
        int s = k * 256 + tid;
        attn[(size_t)s * BSZ + b] = e[k] * inv;
    }
}

// ---------------------------------------------------------------------------
// ctx[b][c] = sum_s attn[s][b] * hids[s][b][c]   (fp32 source, coalesced)
// ---------------------------------------------------------------------------
__global__ __launch_bounds__(256)
void ctx_kernel(const float* __restrict__ hids, const float* __restrict__ attn,
                float* __restrict__ ctx)
{
    const int b   = blockIdx.x;
    const int s0  = blockIdx.y * (SRC_LEN / 8);
    const int tid = threadIdx.x;

    float4 acc = make_float4(0.f, 0.f, 0.f, 0.f);
    for (int s = s0; s < s0 + SRC_LEN / 8; ++s) {
        float w = attn[(size_t)s * BSZ + b];
        if (w != 0.f) {
            float4 h = *reinterpret_cast<const float4*>(
                &hids[((size_t)s * BSZ + b) * CDIM + tid * 4]);
            acc.x = fmaf(w, h.x, acc.x);
            acc.y = fmaf(w, h.y, acc.y);
            acc.z = fmaf(w, h.z, acc.z);
            acc.w = fmaf(w, h.w, acc.w);
        }
    }
    float* dst = &ctx[(size_t)b * CDIM + tid * 4];
    atomicAdd(dst + 0, acc.x);
    atomicAdd(dst + 1, acc.y);
    atomicAdd(dst + 2, acc.z);
    atomicAdd(dst + 3, acc.w);
}

// ---------------------------------------------------------------------------
extern "C" void kernel_launch(void* const* d_in, const int* in_sizes, int n_in,
                              void* d_out, int out_size, void* d_ws, size_t ws_size,
                              hipStream_t stream)
{
    const float* dsr   = (const float*)d_in[0];
    const float* hids  = (const float*)d_in[1];
    const int*   lens  = (const int*)  d_in[2];
    const float* W_enc = (const float*)d_in[3];
    const float* b_enc = (const float*)d_in[4];
    const float* W_dec = (const float*)d_in[5];
    const float* b_dec = (const float*)d_in[6];
    const float* v     = (const float*)d_in[7];

    float* out  = (float*)d_out;
    float* ctx  = out;                       // [64*1024]
    float* attn = out + BSZ * CDIM;          // [1024*64] scores -> probs

    const size_t decb_b = (size_t)BSZ * ADIM * 4;     // 256 KB
    const size_t wf16_b = (size_t)ADIM * KDIM * 2;    // 2 MB
    const size_t af16_b = (size_t)MROWS * KDIM * 2;   // 128 MB

    float*    decb = (float*)d_ws;
    _Float16* Wt   = (_Float16*)((char*)d_ws + decb_b);
    _Float16* At   = (_Float16*)((char*)d_ws + decb_b + wf16_b);

    const bool fast = ws_size >= decb_b + wf16_b + af16_b;

    hipMemsetAsync(d_out, 0, (size_t)(BSZ * CDIM + SRC_LEN * BSZ) * sizeof(float), stream);
    hipMemsetAsync(d_ws, 0, decb_b, stream);   // decb is an atomic target

    dec_kernel<<<dim3(16, 4), 256, 0, stream>>>(dsr, W_dec, decb);

    if (fast) {
        convert_tiled_kernel<<<(ADIM / 128) * 16 * 4, 256, 0, stream>>>(W_enc, Wt);
        convert_tiled_kernel<<<(MROWS / 128) * 16 * 4, 256, 0, stream>>>(hids, At);
        enc_score_direct<<<4096, 256, 0, stream>>>(At, Wt, decb, b_enc, b_dec, v, attn);
    } else {
        convert8_kernel<<<ADIM * KDIM / 8 / 256, 256, 0, stream>>>(W_enc, Wt);
        enc_score_fallback<<<4096, 256, 0, stream>>>(hids, Wt, decb, b_enc, b_dec, v, attn);
    }
    softmax_kernel<<<BSZ, 256, 0, stream>>>(lens, attn);
    ctx_kernel<<<dim3(BSZ, 8), 256, 0, stream>>>(hids, attn, ctx);
}

// Round 8
// 347.844 us; speedup vs baseline: 5.9742x; 1.0819x over previous
//
#include <hip/hip_runtime.h>
#include <math.h>

#define SRC_LEN  1024
#define BSZ      64
#define CDIM     1024
#define ADIM     1024
#define KDIM     1024
#define MROWS    (SRC_LEN * BSZ)
#define NEG_MASK -1000000.0f

// tiled fp16 layout (256-row tiles): tile = 256 rows x 64 cols,
//   fr = row>>4 (0..15), lr = row&15, cb = col>>3, ce = col&7
//   hw = fr*1024 + cb*128 + lr*8 + ce       (tile = 16384 hw = 32 KB)
// => fragment ds_read_b128 (64 lanes) covers 1KB contiguous -> conflict-free,
//    and global->LDS staging is a plain contiguous copy (identity order).
#define THW256 16384

typedef _Float16 f16x8 __attribute__((ext_vector_type(8)));
typedef _Float16 f16x4 __attribute__((ext_vector_type(4)));
typedef float    f32x4 __attribute__((ext_vector_type(4)));

__device__ __forceinline__ float fast_tanh(float x) {
    float e = __expf(2.0f * x);
    return 1.0f - 2.0f / (e + 1.0f);
}

// async global(16B) -> LDS, per-lane global src, wave-uniform LDS base
__device__ __forceinline__ void gload16(const _Float16* g, _Float16* l) {
    __builtin_amdgcn_global_load_lds(
        (const __attribute__((address_space(1))) unsigned int*)g,
        (__attribute__((address_space(3))) unsigned int*)l, 16, 0, 0);
}

__device__ __forceinline__ f16x8 frag(const _Float16* buf, int fr, int ks,
                                      int g, int lc) {
    return *reinterpret_cast<const f16x8*>(
        &buf[fr * 1024 + ks * 512 + g * 128 + lc * 8]);
}

// ---------------------------------------------------------------------------
// fp32 [rows][1024] -> fp16 tiled, 256-row tiles (tiles: rt*16 + kt).
// Each block covers 256 threads x 8 elems = 2048 hw = 1/8 tile.
// ---------------------------------------------------------------------------
__global__ __launch_bounds__(256)
void convert_tiled256_kernel(const float* __restrict__ in, _Float16* __restrict__ out)
{
    const int bid  = blockIdx.x;
    const int part = bid & 7;            // which eighth of the tile
    const int tile = bid >> 3;           // rt*16 + kt
    const int kt   = tile & 15;
    const int rt   = tile >> 4;
    const int t    = threadIdx.x;
    const int u    = part * 256 + t;     // 8-group index 0..2047
    const int fr   = u >> 7;
    const int cb   = (u >> 4) & 7;
    const int lr   = u & 15;

    const size_t row = (size_t)rt * 256 + fr * 16 + lr;
    const int    col = kt * 64 + cb * 8;

    float4 x = *reinterpret_cast<const float4*>(&in[row * KDIM + col]);
    float4 y = *reinterpret_cast<const float4*>(&in[row * KDIM + col + 4]);
    f16x8 o;
    o[0] = (_Float16)x.x; o[1] = (_Float16)x.y;
    o[2] = (_Float16)x.z; o[3] = (_Float16)x.w;
    o[4] = (_Float16)y.x; o[5] = (_Float16)y.y;
    o[6] = (_Float16)y.z; o[7] = (_Float16)y.w;
    *reinterpret_cast<f16x8*>(&out[(size_t)tile * THW256 + (size_t)u * 8]) = o;
}

// ---------------------------------------------------------------------------
// fp32 -> fp16 linear (fallback path W conversion)
// ---------------------------------------------------------------------------
__global__ __launch_bounds__(256)
void convert8_kernel(const float* __restrict__ in, _Float16* __restrict__ out)
{
    size_t i = ((size_t)blockIdx.x * 256 + threadIdx.x) * 8;
    float4 x = *reinterpret_cast<const float4*>(in + i);
    float4 y = *reinterpret_cast<const float4*>(in + i + 4);
    f16x8 o;
    o[0] = (_Float16)x.x; o[1] = (_Float16)x.y;
    o[2] = (_Float16)x.z; o[3] = (_Float16)x.w;
    o[4] = (_Float16)y.x; o[5] = (_Float16)y.y;
    o[6] = (_Float16)y.z; o[7] = (_Float16)y.w;
    *reinterpret_cast<f16x8*>(out + i) = o;
}

// ---------------------------------------------------------------------------
// decb[b][n] += decoder_state @ W_dec^T  (k-split, atomic; no bias)
// ---------------------------------------------------------------------------
__global__ __launch_bounds__(256)
void dec_kernel(const float* __restrict__ A, const float* __restrict__ W,
                float* __restrict__ out)
{
    const int n0  = blockIdx.x * 64;
    const int k0  = blockIdx.y * 256;
    const int tid = threadIdx.x;
    const int tx  = tid & 15;
    const int ty  = tid >> 4;

    __shared__ float Asl[16][64];
    __shared__ float Bsl[16][64];

    float acc[4][4];
#pragma unroll
    for (int i = 0; i < 4; ++i)
#pragma unroll
        for (int j = 0; j < 4; ++j) acc[i][j] = 0.f;

    const int lr = tid >> 2;
    const int lk = (tid & 3) * 4;

    for (int kb = k0; kb < k0 + 256; kb += 16) {
        float4 a4 = *reinterpret_cast<const float4*>(&A[(size_t)lr * KDIM + kb + lk]);
        float4 b4 = *reinterpret_cast<const float4*>(&W[(size_t)(n0 + lr) * KDIM + kb + lk]);
        __syncthreads();
        Asl[lk + 0][lr] = a4.x; Asl[lk + 1][lr] = a4.y;
        Asl[lk + 2][lr] = a4.z; Asl[lk + 3][lr] = a4.w;
        Bsl[lk + 0][lr] = b4.x; Bsl[lk + 1][lr] = b4.y;
        Bsl[lk + 2][lr] = b4.z; Bsl[lk + 3][lr] = b4.w;
        __syncthreads();
#pragma unroll
        for (int k = 0; k < 16; ++k) {
            float4 av = *reinterpret_cast<const float4*>(&Asl[k][ty * 4]);
            float4 bv = *reinterpret_cast<const float4*>(&Bsl[k][tx * 4]);
            float am[4] = {av.x, av.y, av.z, av.w};
            float bn[4] = {bv.x, bv.y, bv.z, bv.w};
#pragma unroll
            for (int i = 0; i < 4; ++i)
#pragma unroll
                for (int j = 0; j < 4; ++j)
                    acc[i][j] = fmaf(am[i], bn[j], acc[i][j]);
        }
    }
#pragma unroll
    for (int i = 0; i < 4; ++i) {
        int m = ty * 4 + i;
#pragma unroll
        for (int j = 0; j < 4; ++j) {
            int n = n0 + tx * 4 + j;
            atomicAdd(&out[(size_t)m * ADIM + n], acc[i][j]);
        }
    }
}

// ---------------------------------------------------------------------------
// FAST PATH: 256x256 tile, BK=64, 8 waves (2Mx4N), wave tile 128x64.
// 4 phases per K-tile: {ds_read subtile || stage-next gloads -> barrier ->
// lgkmcnt(0) -> setprio(1) -> 16 MFMA -> setprio(0) -> barrier}.
// Stages issued phases 0-1, drained once at phase 3. Fused tanh+v epilogue.
// ---------------------------------------------------------------------------
__global__ __launch_bounds__(512, 1)
void enc_score_256(const _Float16* __restrict__ At,   // [256*16] tiles
                   const _Float16* __restrict__ Bt,   // [4*16] tiles
                   const float* __restrict__ decb,    // [64][1024] (no bias)
                   const float* __restrict__ be,      // b_enc
                   const float* __restrict__ bd,      // b_dec
                   const float* __restrict__ v,       // [1024]
                   float* __restrict__ scores)        // [65536]
{
    // nwg=1024, XCD-grouped: the 4 nbt-sharers of one mb on one XCD.
    const int bid = blockIdx.x;
    const int nbt = (bid >> 3) & 3;
    const int mb  = (bid & 7) + ((bid >> 5) << 3);
    const int m0 = mb * 256, n0 = nbt * 256;
    const int tid  = threadIdx.x;
    const int lane = tid & 63;
    const int wid  = tid >> 6;          // 0..7
    const int wm   = wid >> 2;          // 0..1
    const int wn   = wid & 3;           // 0..3
    const int lc   = lane & 15, g = lane >> 4;

    __shared__ __align__(16) _Float16 As[2][THW256];   // 64 KB
    __shared__ __align__(16) _Float16 Bs[2][THW256];   // 64 KB

    f32x4 acc[8][4];
#pragma unroll
    for (int i = 0; i < 8; ++i)
#pragma unroll
        for (int j = 0; j < 4; ++j) acc[i][j] = (f32x4){0.f, 0.f, 0.f, 0.f};

    const _Float16* Abase = At + (size_t)(mb * 16) * THW256;
    const _Float16* Bbase = Bt + (size_t)(nbt * 16) * THW256;

    // ---- prologue: stage K-tile 0 into buffer 0 (8 gloads/wave) ----
#pragma unroll
    for (int i = 0; i < 4; ++i) {
        int c = wid * 4 + i;                  // chunk 0..31, 1KB each
        gload16(Abase + c * 512 + lane * 8, &As[0][c * 512]);
        gload16(Bbase + c * 512 + lane * 8, &Bs[0][c * 512]);
    }
    asm volatile("s_waitcnt vmcnt(0)" ::: "memory");
    __builtin_amdgcn_s_barrier();
    asm volatile("" ::: "memory");

    for (int kt = 0; kt < 16; ++kt) {
        const int cur = kt & 1;
        const _Float16* Acur = As[cur];
        const _Float16* Bcur = Bs[cur];
        _Float16* Anxt = As[cur ^ 1];
        _Float16* Bnxt = Bs[cur ^ 1];
        const _Float16* Ag = Abase + (size_t)(kt + 1) * THW256;
        const _Float16* Bg = Bbase + (size_t)(kt + 1) * THW256;
        const bool pre = (kt < 15);

        f16x8 af[4], bf[4];

        // ===== phase 0: ks=0, mi 0..3  (+ stage A of kt+1) =====
#pragma unroll
        for (int ni = 0; ni < 4; ++ni) bf[ni] = frag(Bcur, wn * 4 + ni, 0, g, lc);
#pragma unroll
        for (int i = 0; i < 4; ++i)    af[i]  = frag(Acur, wm * 8 + i, 0, g, lc);
        if (pre) {
#pragma unroll
            for (int i = 0; i < 4; ++i) {
                int c = wid * 4 + i;
                gload16(Ag + c * 512 + lane * 8, Anxt + c * 512);
            }
        }
        __builtin_amdgcn_s_barrier();
        asm volatile("s_waitcnt lgkmcnt(0)" ::: "memory");
        __builtin_amdgcn_sched_barrier(0);
        __builtin_amdgcn_s_setprio(1);
#pragma unroll
        for (int i = 0; i < 4; ++i)
#pragma unroll
            for (int ni = 0; ni < 4; ++ni)
                acc[i][ni] = __builtin_amdgcn_mfma_f32_16x16x32_f16(
                    af[i], bf[ni], acc[i][ni], 0, 0, 0);
        __builtin_amdgcn_s_setprio(0);
        __builtin_amdgcn_s_barrier();

        // ===== phase 1: ks=0, mi 4..7  (+ stage B of kt+1) =====
#pragma unroll
        for (int i = 0; i < 4; ++i) af[i] = frag(Acur, wm * 8 + 4 + i, 0, g, lc);
        if (pre) {
#pragma unroll
            for (int i = 0; i < 4; ++i) {
                int c = wid * 4 + i;
                gload16(Bg + c * 512 + lane * 8, Bnxt + c * 512);
            }
        }
        __builtin_amdgcn_s_barrier();
        asm volatile("s_waitcnt lgkmcnt(0)" ::: "memory");
        __builtin_amdgcn_sched_barrier(0);
        __builtin_amdgcn_s_setprio(1);
#pragma unroll
        for (int i = 0; i < 4; ++i)
#pragma unroll
            for (int ni = 0; ni < 4; ++ni)
                acc[4 + i][ni] = __builtin_amdgcn_mfma_f32_16x16x32_f16(
                    af[i], bf[ni], acc[4 + i][ni], 0, 0, 0);
        __builtin_amdgcn_s_setprio(0);
        __builtin_amdgcn_s_barrier();

        // ===== phase 2: ks=1, mi 0..3 =====
#pragma unroll
        for (int ni = 0; ni < 4; ++ni) bf[ni] = frag(Bcur, wn * 4 + ni, 1, g, lc);
#pragma unroll
        for (int i = 0; i < 4; ++i)    af[i]  = frag(Acur, wm * 8 + i, 1, g, lc);
        __builtin_amdgcn_s_barrier();
        asm volatile("s_waitcnt lgkmcnt(0)" ::: "memory");
        __builtin_amdgcn_sched_barrier(0);
        __builtin_amdgcn_s_setprio(1);
#pragma unroll
        for (int i = 0; i < 4; ++i)
#pragma unroll
            for (int ni = 0; ni < 4; ++ni)
                acc[i][ni] = __builtin_amdgcn_mfma_f32_16x16x32_f16(
                    af[i], bf[ni], acc[i][ni], 0, 0, 0);
        __builtin_amdgcn_s_setprio(0);
        __builtin_amdgcn_s_barrier();

        // ===== phase 3: ks=1, mi 4..7  (+ drain next-tile stages) =====
#pragma unroll
        for (int i = 0; i < 4; ++i) af[i] = frag(Acur, wm * 8 + 4 + i, 1, g, lc);
        __builtin_amdgcn_s_barrier();
        asm volatile("s_waitcnt lgkmcnt(0)" ::: "memory");
        __builtin_amdgcn_sched_barrier(0);
        __builtin_amdgcn_s_setprio(1);
#pragma unroll
        for (int i = 0; i < 4; ++i)
#pragma unroll
            for (int ni = 0; ni < 4; ++ni)
                acc[4 + i][ni] = __builtin_amdgcn_mfma_f32_16x16x32_f16(
                    af[i], bf[ni], acc[4 + i][ni], 0, 0, 0);
        __builtin_amdgcn_s_setprio(0);
        if (pre) asm volatile("s_waitcnt vmcnt(0)" ::: "memory");
        __builtin_amdgcn_s_barrier();
        asm volatile("" ::: "memory");
    }

    // ---- fused epilogue: tanh + v-dot + reduce ----
    __syncthreads();

    float psum[8][4];
#pragma unroll
    for (int mi = 0; mi < 8; ++mi)
#pragma unroll
        for (int r = 0; r < 4; ++r) psum[mi][r] = 0.f;

#pragma unroll
    for (int mi = 0; mi < 8; ++mi) {
#pragma unroll
        for (int ni = 0; ni < 4; ++ni) {
            int n = n0 + wn * 64 + ni * 16 + lc;
            float vn = v[n];
            float bb = be[n] + bd[n];
#pragma unroll
            for (int r = 0; r < 4; ++r) {
                int b = ((mi & 3) * 16) + g * 4 + r;   // row & 63
                float x = acc[mi][ni][r] + decb[(size_t)b * ADIM + n] + bb;
                psum[mi][r] = fmaf(fast_tanh(x), vn, psum[mi][r]);
            }
        }
    }
#pragma unroll
    for (int mi = 0; mi < 8; ++mi)
#pragma unroll
        for (int r = 0; r < 4; ++r) {
            float s = psum[mi][r];
            s += __shfl_xor(s, 1);
            s += __shfl_xor(s, 2);
            s += __shfl_xor(s, 4);
            s += __shfl_xor(s, 8);
            psum[mi][r] = s;
        }

    float* red = reinterpret_cast<float*>(&As[0][0]);   // [256][4]
    if (lc == 0) {
#pragma unroll
        for (int mi = 0; mi < 8; ++mi)
#pragma unroll
            for (int r = 0; r < 4; ++r) {
                int row = wm * 128 + mi * 16 + g * 4 + r;
                red[row * 4 + wn] = psum[mi][r];
            }
    }
    __syncthreads();
    if (tid < 256)
        atomicAdd(&scores[m0 + tid],
                  red[tid * 4] + red[tid * 4 + 1] + red[tid * 4 + 2] + red[tid * 4 + 3]);
}

// ---------------------------------------------------------------------------
// FALLBACK (ws too small): reg-staged fp32-A version.
// ---------------------------------------------------------------------------
__global__ __launch_bounds__(256)
void enc_score_fallback(const float* __restrict__ A,
                        const _Float16* __restrict__ Bw,
                        const float* __restrict__ decb,
                        const float* __restrict__ be,
                        const float* __restrict__ bd,
                        const float* __restrict__ v,
                        float* __restrict__ scores)
{
    const int bid = blockIdx.x;
    const int nb  = (bid >> 3) & 7;
    const int mb  = (bid & 7) + ((bid >> 6) << 3);
    const int m0 = mb * 128, n0 = nb * 128;
    const int tid  = threadIdx.x;
    const int lane = tid & 63;
    const int wid  = tid >> 6;
    const int wm   = wid >> 1, wn = wid & 1;
    const int lc   = lane & 15, g = lane >> 4;

    __shared__ __align__(16) _Float16 As[128 * 64];
    __shared__ __align__(16) _Float16 Bs[128 * 64];

    const int srow = tid >> 1;
    const int scol = (tid & 1) * 32;
    const int sw   = (srow & 7) << 3;

    f32x4 acc[4][4];
#pragma unroll
    for (int i = 0; i < 4; ++i)
#pragma unroll
        for (int j = 0; j < 4; ++j) acc[i][j] = (f32x4){0.f, 0.f, 0.f, 0.f};

    const float*    Aptr = A  + (size_t)(m0 + srow) * KDIM + scol;
    const _Float16* Bptr = Bw + (size_t)(n0 + srow) * KDIM + scol;

    float4 aR[8];
    uint4  bR[4];
#pragma unroll
    for (int i = 0; i < 8; ++i) aR[i] = reinterpret_cast<const float4*>(Aptr)[i];
#pragma unroll
    for (int i = 0; i < 4; ++i) bR[i] = reinterpret_cast<const uint4*>(Bptr)[i];

    for (int kb = 0; kb < KDIM; kb += 64) {
        __syncthreads();
#pragma unroll
        for (int w = 0; w < 4; ++w) {
            float4 x = aR[2 * w], y = aR[2 * w + 1];
            f16x8 p;
            p[0] = (_Float16)x.x; p[1] = (_Float16)x.y;
            p[2] = (_Float16)x.z; p[3] = (_Float16)x.w;
            p[4] = (_Float16)y.x; p[5] = (_Float16)y.y;
            p[6] = (_Float16)y.z; p[7] = (_Float16)y.w;
            int hw = (srow * 64 + scol + 8 * w) ^ sw;
            *reinterpret_cast<f16x8*>(&As[hw]) = p;
            *reinterpret_cast<uint4*>(&Bs[hw]) = bR[w];
        }
        __syncthreads();
        if (kb + 64 < KDIM) {
#pragma unroll
            for (int i = 0; i < 8; ++i)
                aR[i] = reinterpret_cast<const float4*>(Aptr + kb + 64)[i];
#pragma unroll
            for (int i = 0; i < 4; ++i)
                bR[i] = reinterpret_cast<const uint4*>(Bptr + kb + 64)[i];
        }
#pragma unroll
        for (int ks = 0; ks < 2; ++ks) {
            f16x8 af[4], bf[4];
#pragma unroll
            for (int mi = 0; mi < 4; ++mi) {
                int r  = wm * 64 + mi * 16 + lc;
                int hw = (r * 64 + ks * 32 + g * 8) ^ ((r & 7) << 3);
                af[mi] = *reinterpret_cast<const f16x8*>(&As[hw]);
            }
#pragma unroll
            for (int ni = 0; ni < 4; ++ni) {
                int r  = wn * 64 + ni * 16 + lc;
                int hw = (r * 64 + ks * 32 + g * 8) ^ ((r & 7) << 3);
                bf[ni] = *reinterpret_cast<const f16x8*>(&Bs[hw]);
            }
#pragma unroll
            for (int mi = 0; mi < 4; ++mi)
#pragma unroll
                for (int ni = 0; ni < 4; ++ni)
                    acc[mi][ni] = __builtin_amdgcn_mfma_f32_16x16x32_f16(
                        af[mi], bf[ni], acc[mi][ni], 0, 0, 0);
        }
    }

    __syncthreads();

    float psum[4][4];
#pragma unroll
    for (int mi = 0; mi < 4; ++mi)
#pragma unroll
        for (int r = 0; r < 4; ++r) psum[mi][r] = 0.f;

#pragma unroll
    for (int mi = 0; mi < 4; ++mi) {
#pragma unroll
        for (int ni = 0; ni < 4; ++ni) {
            int n = n0 + wn * 64 + ni * 16 + lc;
            float vn = v[n];
            float bb = be[n] + bd[n];
#pragma unroll
            for (int r = 0; r < 4; ++r) {
                int b = mi * 16 + g * 4 + r;
                float x = acc[mi][ni][r] + decb[(size_t)b * ADIM + n] + bb;
                psum[mi][r] = fmaf(fast_tanh(x), vn, psum[mi][r]);
            }
        }
    }
#pragma unroll
    for (int mi = 0; mi < 4; ++mi)
#pragma unroll
        for (int r = 0; r < 4; ++r) {
            float s = psum[mi][r];
            s += __shfl_xor(s, 1);
            s += __shfl_xor(s, 2);
            s += __shfl_xor(s, 4);
            s += __shfl_xor(s, 8);
            psum[mi][r] = s;
        }

    float* red = reinterpret_cast<float*>(As);
    if (lc == 0) {
#pragma unroll
        for (int mi = 0; mi < 4; ++mi)
#pragma unroll
            for (int r = 0; r < 4; ++r) {
                int row = wm * 64 + mi * 16 + g * 4 + r;
                red[row * 2 + wn] = psum[mi][r];
            }
    }
    __syncthreads();
    if (tid < 128)
        atomicAdd(&scores[m0 + tid], red[tid * 2] + red[tid * 2 + 1]);
}

// ---------------------------------------------------------------------------
// Masked softmax over S per batch column, in place. One block per b.
// ---------------------------------------------------------------------------
__global__ __launch_bounds__(256)
void softmax_kernel(const int* __restrict__ lens, float* __restrict__ attn)
{
    const int b   = blockIdx.x;
    const int tid = threadIdx.x;
    const int len = lens[b];

    float sc[4];
#pragma unroll
    for (int k = 0; k < 4; ++k) {
        int s = k * 256 + tid;
        float x = attn[(size_t)s * BSZ + b];
        sc[k] = (s < len) ? x : NEG_MASK;
    }

    __shared__ float red[8];

    float m = fmaxf(fmaxf(sc[0], sc[1]), fmaxf(sc[2], sc[3]));
#pragma unroll
    for (int off = 32; off > 0; off >>= 1) m = fmaxf(m, __shfl_xor(m, off));
    if ((tid & 63) == 0) red[tid >> 6] = m;
    __syncthreads();
    m = fmaxf(fmaxf(red[0], red[1]), fmaxf(red[2], red[3]));

    float e[4];
    float sum = 0.f;
#pragma unroll
    for (int k = 0; k < 4; ++k) { e[k] = expf(sc[k] - m); sum += e[k]; }
#pragma unroll
    for (int off = 32; off > 0; off >>= 1) sum += __shfl_xor(sum, off);
    __syncthreads();
    if ((tid & 63) == 0) red[4 + (tid >> 6)] = sum;
    __syncthreads();
    float total = red[4] + red[5] + red[6] + red[7];
    float inv = 1.f / total;

#pragma unroll
    for (int k = 0; k < 4; ++k) {
        int s = k * 256 + tid;
        attn[(size_t)s * BSZ + b] = e[k] * inv;
    }
}

// ---------------------------------------------------------------------------
// ctx[b][c] = sum_s attn[s][b] * hids[s][b][c]   (fp32 source, coalesced)
// ---------------------------------------------------------------------------
__global__ __launch_bounds__(256)
void ctx_kernel(const float* __restrict__ hids, const float* __restrict__ attn,
                float* __restrict__ ctx)
{
    const int b   = blockIdx.x;
    const int s0  = blockIdx.y * (SRC_LEN / 8);
    const int tid = threadIdx.x;

    float4 acc = make_float4(0.f, 0.f, 0.f, 0.f);
    for (int s = s0; s < s0 + SRC_LEN / 8; ++s) {
        float w = attn[(size_t)s * BSZ + b];
        if (w != 0.f) {
            float4 h = *reinterpret_cast<const float4*>(
                &hids[((size_t)s * BSZ + b) * CDIM + tid * 4]);
            acc.x = fmaf(w, h.x, acc.x);
            acc.y = fmaf(w, h.y, acc.y);
            acc.z = fmaf(w, h.z, acc.z);
            acc.w = fmaf(w, h.w, acc.w);
        }
    }
    float* dst = &ctx[(size_t)b * CDIM + tid * 4];
    atomicAdd(dst + 0, acc.x);
    atomicAdd(dst + 1, acc.y);
    atomicAdd(dst + 2, acc.z);
    atomicAdd(dst + 3, acc.w);
}

// ---------------------------------------------------------------------------
extern "C" void kernel_launch(void* const* d_in, const int* in_sizes, int n_in,
                              void* d_out, int out_size, void* d_ws, size_t ws_size,
                              hipStream_t stream)
{
    const float* dsr   = (const float*)d_in[0];
    const float* hids  = (const float*)d_in[1];
    const int*   lens  = (const int*)  d_in[2];
    const float* W_enc = (const float*)d_in[3];
    const float* b_enc = (const float*)d_in[4];
    const float* W_dec = (const float*)d_in[5];
    const float* b_dec = (const float*)d_in[6];
    const float* v     = (const float*)d_in[7];

    float* out  = (float*)d_out;
    float* ctx  = out;                       // [64*1024]
    float* attn = out + BSZ * CDIM;          // [1024*64] scores -> probs

    const size_t decb_b = (size_t)BSZ * ADIM * 4;     // 256 KB
    const size_t wf16_b = (size_t)ADIM * KDIM * 2;    // 2 MB
    const size_t af16_b = (size_t)MROWS * KDIM * 2;   // 128 MB

    float*    decb = (float*)d_ws;
    _Float16* Wt   = (_Float16*)((char*)d_ws + decb_b);
    _Float16* At   = (_Float16*)((char*)d_ws + decb_b + wf16_b);

    const bool fast = ws_size >= decb_b + wf16_b + af16_b;

    hipMemsetAsync(d_out, 0, (size_t)(BSZ * CDIM + SRC_LEN * BSZ) * sizeof(float), stream);
    hipMemsetAsync(d_ws, 0, decb_b, stream);   // decb is an atomic target

    dec_kernel<<<dim3(16, 4), 256, 0, stream>>>(dsr, W_dec, decb);

    if (fast) {
        convert_tiled256_kernel<<<(ADIM / 256) * 16 * 8, 256, 0, stream>>>(W_enc, Wt);
        convert_tiled256_kernel<<<(MROWS / 256) * 16 * 8, 256, 0, stream>>>(hids, At);
        enc_score_256<<<1024, 512, 0, stream>>>(At, Wt, decb, b_enc, b_dec, v, attn);
    } else {
        convert8_kernel<<<ADIM * KDIM / 8 / 256, 256, 0, stream>>>(W_enc, Wt);
        enc_score_fallback<<<4096, 256, 0, stream>>>(hids, Wt, decb, b_enc, b_dec, v, attn);
    }
    softmax_kernel<<<BSZ, 256, 0, stream>>>(lens, attn);
    ctx_kernel<<<dim3(BSZ, 8), 256, 0, stream>>>(hids, attn, ctx);
}